// Round 13
// baseline (765.825 us; speedup 1.0000x reference)
//
#include <hip/hip_runtime.h>
#include <hip/hip_bf16.h>

#define DEV __device__ __forceinline__

namespace {

constexpr int Bn  = 4, SEQ = 1024, NV = 32, PL = 16, D = 512, H = 8, DFF = 2048;
constexpr int P   = SEQ / PL;    // 64 patches
constexpr int L   = P * NV;      // 2048 tokens per batch
constexpr int M   = Bn * L;      // 8192 total token rows
constexpr int WIN = 4;

using short8   = __attribute__((ext_vector_type(8))) short;
using ushort8  = __attribute__((ext_vector_type(8))) unsigned short;
using ushort4  = __attribute__((ext_vector_type(4))) unsigned short;
using float4v  = __attribute__((ext_vector_type(4))) float;

DEV float b2f(unsigned short u) { return __uint_as_float(((unsigned)u) << 16); }
DEV unsigned short f2b(float f) {   // RNE (used where bias matters)
  unsigned fb = __float_as_uint(f);
  return (unsigned short)((fb + 0x7FFFu + ((fb >> 16) & 1u)) >> 16);
}
DEV unsigned short f2bt(float f) {  // truncation: 1 VALU op
  return (unsigned short)(__float_as_uint(f) >> 16);
}
// flag-dispatched float load from an input tensor: bf=1 -> bf16, 0 -> fp32
DEV float ldf(const void* p, size_t idx, int bf) {
  if (bf) return b2f(((const unsigned short*)p)[idx]);
  return ((const float*)p)[idx];
}
// async global->LDS 16B: lds dest = wave-uniform base + lane*16
DEV void gll16(const void* gp, void* lp) {
  __builtin_amdgcn_global_load_lds(
      (const __attribute__((address_space(1))) void*)gp,
      (__attribute__((address_space(3))) void*)lp, 16, 0, 0);
}

// ---------------------------------------------------------------------------
// k_setup: detect float dtype + mask format, canonicalize mask, count masked.
// ---------------------------------------------------------------------------
__global__ void k_setup(const void* gf, const void* mask_raw, int* mask_i,
                        int* flags, float* scal) {
  __shared__ int s_gt1, s_oth, s_cnt;
  int tid = threadIdx.x;
  if (tid == 0) { s_gt1 = 0; s_oth = 0; s_cnt = 0; }
  __syncthreads();
  const unsigned* mw = (const unsigned*)mask_raw;
  int gt1 = 0, oth = 0;
  for (int i = tid; i < 2048; i += 256) {
    unsigned w = mw[i];
    if (w > 1u) { gt1 = 1; if (w != 0x3F800000u) oth = 1; }
  }
  if (gt1) atomicOr(&s_gt1, 1);
  if (oth) atomicOr(&s_oth, 1);
  __syncthreads();
  int fmt = (!s_gt1) ? 0 : (!s_oth ? 1 : 2);  // 0=int32, 1=f32, 2=bytes
  int cnt = 0;
  for (int i = tid; i < Bn * P * NV; i += 256) {
    int m;
    if (fmt == 0)      m = ((const int*)mask_raw)[i] != 0;
    else if (fmt == 1) m = ((const float*)mask_raw)[i] != 0.0f;
    else               m = ((const unsigned char*)mask_raw)[i] != 0;
    mask_i[i] = m; cnt += m;
  }
  atomicAdd(&s_cnt, cnt);
  __syncthreads();
  if (tid == 0) {
    unsigned w = *(const unsigned*)gf;
    flags[0] = ((w & 0xFFFFu) == 0x3F80u) ? 1 : 0;
    flags[1] = s_cnt;
    scal[0] = 0.f;
  }
}

// ---------------------------------------------------------------------------
// k_prep: blocks 0..31 -> per-(b,v) stats; blocks 32.. -> gather biases,
// final-LN weights (fp32), b_proj (fp32), WpT (bf16 [t][d]), and ALL
// per-layer LN gamma/beta as fp32 (R10). lnAll: [l][phase][g:512|b:512].
// ---------------------------------------------------------------------------
__global__ void k_prep(const void* x, const void* bq, const void* bk,
                       const void* bv, const void* bo, const void* b1,
                       const void* b2, const void* gf, const void* bff,
                       const void* Wp, const void* bp, const void* g1,
                       const void* be1, const void* g2, const void* be2,
                       const int* flags, float* means, float* stdev,
                       float* biasf, float* lnw, unsigned short* WpT,
                       float* lnAll) {
  int bf = flags[0];
  int tid = threadIdx.x;
  if (blockIdx.x < 32) {
    int bv_ = blockIdx.x * 4 + (tid >> 6);
    int b = bv_ >> 5, v = bv_ & 31;
    int lane = tid & 63;
    float s = 0.f, s2 = 0.f;
    for (int t = lane; t < SEQ; t += 64) {
      float val = ldf(x, (size_t)b * SEQ * NV + (size_t)t * NV + v, bf);
      s += val; s2 += val * val;
    }
    for (int off = 32; off; off >>= 1) {
      s += __shfl_xor(s, off); s2 += __shfl_xor(s2, off);
    }
    if (lane == 0) {
      float m = s / (float)SEQ;
      means[bv_] = m;
      stdev[bv_] = sqrtf(s2 / (float)SEQ - m * m + 1e-5f);
    }
    return;
  }
  int i = (blockIdx.x - 32) * 256 + tid;
  if (i < 18432) {
    int l = i / 4608, r = i % 4608;
    if (r < 1536) {
      float v = (r < 512) ? ldf(bq, l * 512 + r, bf)
              : (r < 1024) ? ldf(bk, l * 512 + r - 512, bf)
                           : ldf(bv, l * 512 + r - 1024, bf);
      biasf[l * 1536 + r] = v;
    } else if (r < 2048) {
      biasf[6144 + l * 512 + (r - 1536)] = ldf(bo, l * 512 + r - 1536, bf);
    } else if (r < 4096) {
      biasf[8192 + l * 2048 + (r - 2048)] = ldf(b1, l * 2048 + r - 2048, bf);
    } else {
      biasf[16384 + l * 512 + (r - 4096)] = ldf(b2, l * 512 + r - 4096, bf);
    }
  } else if (i < 19456) {
    int j = i - 18432;
    lnw[j] = (j < 512) ? ldf(gf, j, bf) : ldf(bff, j - 512, bf);
  } else if (i < 19472) {
    lnw[1024 + (i - 19456)] = ldf(bp, i - 19456, bf);
  } else if (i < 27664) {
    int j = i - 19472; int t = j >> 9, d = j & 511;
    WpT[j] = f2b(ldf(Wp, d * 16 + t, bf));
  } else if (i < 35856) {
    int j = i - 27664;
    int l = j >> 11, r = j & 2047;
    int ph = r >> 10, c = r & 1023;
    const void* src = (c < 512) ? (ph ? g2 : g1) : (ph ? be2 : be1);
    lnAll[j] = ldf(src, l * 512 + (c & 511), bf);
  }
}

// ---------------------------------------------------------------------------
// k_transpose_all: all 6 weight transposes in one dispatch.
// dst[l][n][k] (bf16) = src[l][k][n]. 32x32 LDS tile per block.
// ---------------------------------------------------------------------------
__global__ void k_transpose_all(const void* Wq, const void* Wk, const void* Wv,
                                const void* Wo, const void* W1, const void* W2,
                                unsigned short* qkvT, unsigned short* WoT,
                                unsigned short* W1T, unsigned short* W2T,
                                const int* flags) {
  int bf = flags[0];
  int id = blockIdx.x;
  const void* src; unsigned short* dst;
  int Kd, Nd, l, n0, k0, dstOff = 0;
  size_t srcLS, dstLS;
  if (id < 4096) {
    int tensor = id >> 10, rem = id & 1023;
    l = rem >> 8; int t = rem & 255;
    n0 = (t & 15) * 32; k0 = (t >> 4) * 32;
    Kd = 512; Nd = 512; srcLS = 262144;
    if (tensor == 0)      { src = Wq; dst = qkvT; dstLS = 786432; dstOff = 0; }
    else if (tensor == 1) { src = Wk; dst = qkvT; dstLS = 786432; dstOff = 262144; }
    else if (tensor == 2) { src = Wv; dst = qkvT; dstLS = 786432; dstOff = 524288; }
    else                  { src = Wo; dst = WoT;  dstLS = 262144; }
  } else if (id < 8192) {
    int rem = id - 4096; l = rem >> 10; int t = rem & 1023;
    n0 = (t & 63) * 32; k0 = (t >> 6) * 32;
    Kd = 512; Nd = 2048; srcLS = 1048576; src = W1; dst = W1T; dstLS = 1048576;
  } else {
    int rem = id - 8192; l = rem >> 10; int t = rem & 1023;
    n0 = (t & 15) * 32; k0 = (t >> 4) * 32;
    Kd = 2048; Nd = 512; srcLS = 1048576; src = W2; dst = W2T; dstLS = 1048576;
  }
  int tx = threadIdx.x & 31, ty = threadIdx.x >> 5;
  __shared__ float tile[32][33];
  for (int rr = ty; rr < 32; rr += 8)
    tile[rr][tx] =
        ldf(src, (size_t)l * srcLS + (size_t)(k0 + rr) * Nd + n0 + tx, bf);
  __syncthreads();
  for (int rr = ty; rr < 32; rr += 8)
    dst[(size_t)l * dstLS + dstOff + (size_t)(n0 + rr) * Kd + k0 + tx] =
        f2b(tile[tx][rr]);
}

// ---------------------------------------------------------------------------
// k_embed (R11, kept): one block per (b,p) patch, 512 thr. We staged ONCE in
// LDS as float4 [t][d4] (32 KB). Thread (v = tid>>4, c = tid&15) computes
// token v, d4-set c+16k; ushort4 stores coalesce. Bit-identical math.
// ---------------------------------------------------------------------------
__global__ __launch_bounds__(512) void k_embed(
    const void* x, const void* We, const void* be, const int* flags,
    const int* mask_i, const float* means, const float* stdev,
    float* patches, unsigned short* tok) {
  int bp = blockIdx.x;              // Bn*P = 256 blocks
  int b = bp >> 6, p = bp & 63;
  int bf = flags[0];
  __shared__ float4v sWe[16 * 128];   // [t][d4], 32 KB
  __shared__ float4v sbe[128];
  __shared__ float spv[32][17];
  int tid = threadIdx.x;
  for (int i = tid; i < 2048; i += 512) {
    float4v w4;
    w4[0] = ldf(We, (size_t)i * 4 + 0, bf);
    w4[1] = ldf(We, (size_t)i * 4 + 1, bf);
    w4[2] = ldf(We, (size_t)i * 4 + 2, bf);
    w4[3] = ldf(We, (size_t)i * 4 + 3, bf);
    sWe[i] = w4;
  }
  if (tid < 128) {
    float4v b4;
    b4[0] = ldf(be, tid * 4 + 0, bf);
    b4[1] = ldf(be, tid * 4 + 1, bf);
    b4[2] = ldf(be, tid * 4 + 2, bf);
    b4[3] = ldf(be, tid * 4 + 3, bf);
    sbe[tid] = b4;
  }
  {
    int t = tid >> 5, v = tid & 31;
    float m = means[b * NV + v], sd = stdev[b * NV + v];
    float val =
        (ldf(x, (size_t)b * SEQ * NV + (size_t)(p * PL + t) * NV + v, bf) -
         m) / sd;
    spv[v][t] = val;
    patches[(size_t)((b << 11) + (p << 5) + v) * PL + t] = val;
  }
  __syncthreads();
  int v = tid >> 4, c = tid & 15;
  int idx = (b << 11) + (p << 5) + v;
  int masked = mask_i[idx];
  float pv[16];
#pragma unroll
  for (int t = 0; t < 16; t++) pv[t] = spv[v][t];
  unsigned short* orow = tok + (size_t)idx * D;
#pragma unroll
  for (int k = 0; k < 8; k++) {
    int d4 = c + (k << 4);
    float4v acc = sbe[d4];
#pragma unroll
    for (int t = 0; t < 16; t++) {
      float4v w4 = sWe[t * 128 + d4];
      acc[0] += pv[t] * w4[0];
      acc[1] += pv[t] * w4[1];
      acc[2] += pv[t] * w4[2];
      acc[3] += pv[t] * w4[3];
    }
    ushort4 ou;
    ou[0] = masked ? (unsigned short)0 : f2b(acc[0]);
    ou[1] = masked ? (unsigned short)0 : f2b(acc[1]);
    ou[2] = masked ? (unsigned short)0 : f2b(acc[2]);
    ou[3] = masked ? (unsigned short)0 : f2b(acc[3]);
    *(ushort4*)(orow + d4 * 4) = ou;
  }
}

// ---------------------------------------------------------------------------
// k_gemm<BM,BN,WN,MW>: C = act(A @ W^T' + bias [+resid]) in bf16. BK=64.
// Linear grid, XCD-swizzled. Epilogue through LDS for coalesced ushort8 IO.
// R13: PER-INSTANTIATION launch bounds via MW (min waves/EU). R11 vs R12
// accounting: the (256,3) clamp HURT the wide FJ=4 tile (VGPR 80->56, 131K
// bank conflicts, QKV 49 us) but HELPED the skinny FJ=1 tile (~25 us/layer
// across Wo+FFN2 — its ~100-reg demand fits the 170-reg budget, occupancy
// 2->3 blocks/CU, no spill). So: wide = MW 1 (unconstrained allocator,
// R12-proven codegen), skinny = MW 3 (R11-proven occupancy win).
// Tile law (R6-R9): QKV/FFN1 wide <128,128,64>, Wo/FFN2 skinny <64,64,16>.
// All constant-trip loops carry #pragma unroll (rule #20).
// ---------------------------------------------------------------------------
template <int BM, int BN, int WN, int MW>
__global__ __launch_bounds__(256, MW) void k_gemm(
    const unsigned short* __restrict__ A, const unsigned short* __restrict__ W,
    const float* __restrict__ bias, const unsigned short* __restrict__ resid,
    unsigned short* __restrict__ C, unsigned short* __restrict__ vTp, int cs,
    int Kk, int act, int nbn) {
  constexpr int FI = 4, FJ = WN / 16, NWN = BN / WN;
  __shared__ __align__(16) char sm[BM * 128 + BN * 128];
  char* As = sm;
  char* Bs = sm + BM * 128;
  unsigned short* Cl = (unsigned short*)sm;
  int tid = threadIdx.x, lane = tid & 63, w = tid >> 6;
  int lane15 = lane & 15, q = lane >> 4;
  int wm = w / NWN, wn = w % NWN;
  int id = blockIdx.x;
  int xcd = id & 7, loc = id >> 3;
  int bn = (loc % nbn) * BN;
  int bm = (xcd * ((int)(gridDim.x >> 3) / nbn) + loc / nbn) * BM;
  int lrow = lane >> 3, lc = lane & 7;
  float4v acc[FI][FJ];
#pragma unroll
  for (int i = 0; i < FI; i++)
#pragma unroll
    for (int j = 0; j < FJ; j++) acc[i][j] = 0;
  for (int k0 = 0; k0 < Kk; k0 += 64) {
    if (k0) __syncthreads();
    for (int i = w; i < BM / 8; i += 4) {
      int row = i * 8 + lrow;
      gll16(A + (size_t)(bm + row) * Kk + k0 + ((lc ^ (row & 7)) << 3),
            As + i * 1024);
    }
    for (int i = w; i < BN / 8; i += 4) {
      int row = i * 8 + lrow;
      gll16(W + (size_t)(bn + row) * Kk + k0 + ((lc ^ (row & 7)) << 3),
            Bs + i * 1024);
    }
    __syncthreads();
    short8 a[2][FI], b[2][FJ];
#pragma unroll
    for (int h = 0; h < 2; h++) {
#pragma unroll
      for (int i = 0; i < FI; i++) {
        int rr = wm * 64 + i * 16 + lane15;
        a[h][i] =
            *(const short8*)(As + rr * 128 + (((h * 4 + q) ^ (rr & 7)) << 4));
      }
#pragma unroll
      for (int j = 0; j < FJ; j++) {
        int rr = wn * WN + j * 16 + lane15;
        b[h][j] =
            *(const short8*)(Bs + rr * 128 + (((h * 4 + q) ^ (rr & 7)) << 4));
      }
    }
#pragma unroll
    for (int h = 0; h < 2; h++)
#pragma unroll
      for (int i = 0; i < FI; i++)
#pragma unroll
        for (int j = 0; j < FJ; j++)
          acc[i][j] = __builtin_amdgcn_mfma_f32_16x16x32_bf16(
              a[h][i], b[h][j], acc[i][j], 0, 0, 0);
  }
  // ---- epilogue through LDS ----
  int vmode = (vTp != nullptr) && (bn >= 1024);
  float oscale = (vTp != nullptr && bn < 512) ? 0.125f : 1.0f;  // q pre-scale
  __syncthreads();  // all MFMAs done reading As/Bs
#pragma unroll
  for (int i = 0; i < FI; i++) {
#pragma unroll
    for (int j = 0; j < FJ; j++) {
      int col = wn * WN + j * 16 + lane15;        // tile-local col
      float bv = bias[bn + col];
#pragma unroll
      for (int r = 0; r < 4; r++) {
        int row = wm * 64 + i * 16 + q * 4 + r;   // tile-local row
        float cv = (acc[i][j][r] + bv) * oscale;
        if (act) {  // fast GELU: x * sigmoid(1.5958x + 0.07135x^3)
          float t = cv * (1.5957692f + 0.0713548f * cv * cv);
          cv = cv / (1.f + __expf(-t));
        }
        if (!vmode)
          Cl[row * BN + (((col >> 3) ^ (row & 7)) << 3) + (col & 7)] = f2bt(cv);
        else
          Cl[col * BM + (((row >> 3) ^ (col & 7)) << 3) + (row & 7)] = f2bt(cv);
      }
    }
  }
  __syncthreads();
  if (!vmode) {
    constexpr int TOT = BM * BN / 8;
    for (int e = tid; e < TOT; e += 256) {
      int rr = e / (BN / 8), c8 = e % (BN / 8);
      ushort8 u = *(const ushort8*)(Cl + rr * BN + ((c8 ^ (rr & 7)) << 3));
      size_t off = (size_t)(bm + rr) * cs + bn + c8 * 8;
      if (resid) {
        ushort8 rv = *(const ushort8*)(resid + off);
#pragma unroll
        for (int t = 0; t < 8; t++) u[t] = f2bt(b2f(u[t]) + b2f(rv[t]));
      }
      *(ushort8*)(C + off) = u;
    }
  } else {
    constexpr int TOT = BM * BN / 8;
    for (int e = tid; e < TOT; e += 256) {
      int cc = e / (BM / 8), t8 = e % (BM / 8);
      ushort8 u = *(const ushort8*)(Cl + cc * BM + ((t8 ^ (cc & 7)) << 3));
      int hd = bn - 1024 + cc;
      int rowg = bm + t8 * 8;
      int bb = rowg >> 11, tokin = rowg & 2047;
      *(ushort8*)(vTp + ((size_t)(bb * 512 + hd)) * 2048 + tokin) = u;
    }
  }
}

// ---------------------------------------------------------------------------
// k_attn: banded MFMA attention, fragment-direct global loads. 19.5 KB LDS,
// VGPR <64 -> 8 blocks/CU. q pre-scaled by 0.125 in QKV GEMM; softmax skips
// max-sub (|s| <~ 5). T5 s_setprio(1) around MFMA clusters (R10 win).
// ---------------------------------------------------------------------------
__global__ __launch_bounds__(256) void k_attn(
    const unsigned short* __restrict__ qk,
    const unsigned short* __restrict__ vT, unsigned short* __restrict__ o) {
  constexpr int SSTR = 304;
  __shared__ __align__(16) unsigned short S[32 * SSTR];
  int id = blockIdx.x;
  int xcd = id & 7, rr_ = id >> 3;
  int p = xcd * 8 + (rr_ & 7);
  int h = (rr_ >> 3) & 7;
  int b = rr_ >> 6;
  int tid = threadIdx.x, lane = tid & 63, w = tid >> 6;
  int lane15 = lane & 15, q = lane >> 4;
  int p0 = max(0, p - WIN), p1 = min(P - 1, p + WIN);
  int nk = (p1 - p0 + 1) * 32;     // multiple of 32, in [160,288]
  int ntiles = nk >> 4;
  size_t base = (size_t)b * L;
  // Q fragments for BOTH m-tiles (A-operand), direct global
  short8 aq[2][2];
  for (int m = 0; m < 2; m++) {
    const unsigned short* qrow =
        qk + (base + p * 32 + m * 16 + lane15) * 1024 + h * 64 + q * 8;
    aq[m][0] = *(const short8*)(qrow);
    aq[m][1] = *(const short8*)(qrow + 32);
  }
  const unsigned short* kbase =
      qk + (base + p0 * 32) * 1024 + 512 + h * 64 + q * 8;
  // phase A: wave w handles nt = w, w+4, ... (no duplicate K loads)
  {
    int nt = w;
    const unsigned short* kr = kbase + (size_t)(nt * 16 + lane15) * 1024;
    short8 c0, c1, n0, n1;
    if (nt < ntiles) {
      c0 = *(const short8*)(kr);
      c1 = *(const short8*)(kr + 32);
    }
    if (nt + 4 < ntiles) {
      kr = kbase + (size_t)((nt + 4) * 16 + lane15) * 1024;
      n0 = *(const short8*)(kr);
      n1 = *(const short8*)(kr + 32);
    }
    for (; nt < ntiles; nt += 4) {
      short8 m0, m1;
      if (nt + 8 < ntiles) {
        kr = kbase + (size_t)((nt + 8) * 16 + lane15) * 1024;
        m0 = *(const short8*)(kr);
        m1 = *(const short8*)(kr + 32);
      }
      __builtin_amdgcn_s_setprio(1);
      for (int m = 0; m < 2; m++) {
        float4v s4 = 0;
        s4 = __builtin_amdgcn_mfma_f32_16x16x32_bf16(aq[m][0], c0, s4, 0, 0, 0);
        s4 = __builtin_amdgcn_mfma_f32_16x16x32_bf16(aq[m][1], c1, s4, 0, 0, 0);
        for (int r = 0; r < 4; r++)
          S[(m * 16 + q * 4 + r) * SSTR + nt * 16 + lane15] = f2b(s4[r]);
      }
      __builtin_amdgcn_s_setprio(0);
      c0 = n0; c1 = n1; n0 = m0; n1 = m1;
    }
  }
  __syncthreads();
  // phase B: softmax without max-sub, b128 LDS IO, trunc P pack
  {
    int row = tid >> 3, c = tid & 7;
    ushort8 eb[5];
    float sum = 0.f;
    for (int k = 0; k < 5; k++) {
      int j0 = c * 8 + k * 64;
      if (j0 < nk) {
        ushort8 u = *(const ushort8*)(S + row * SSTR + j0);
        ushort8 e8;
        for (int t = 0; t < 8; t++) {
          float e = __expf(b2f(u[t]));
          sum += e;
          e8[t] = f2bt(e);
        }
        eb[k] = e8;
      }
    }
    for (int off = 1; off < 8; off <<= 1) sum += __shfl_xor(sum, off);
    float inv = 1.f / sum;
    for (int k = 0; k < 5; k++) {
      int j0 = c * 8 + k * 64;
      if (j0 < nk) {
        ushort8 e8 = eb[k], u;
        for (int t = 0; t < 8; t++) u[t] = f2bt(b2f(e8[t]) * inv);
        *(ushort8*)(S + row * SSTR + j0) = u;
      }
    }
  }
  __syncthreads();
  // phase C: O = P V. Wave w owns column tile w (16 cols), both m-tiles --
  // one V load per kt feeds 2 MFMAs (no duplicate V loads across waves).
  int nkt = nk >> 5;
  const unsigned short* vb =
      vT + (size_t)(b * 512 + h * 64 + w * 16 + lane15) * 2048 + p0 * 32 +
      q * 8;
  const unsigned short* pr0 = S + lane15 * SSTR + q * 8;
  const unsigned short* pr1 = S + (16 + lane15) * SSTR + q * 8;
  float4v oa0 = 0, oa1 = 0;
  short8 ap0 = *(const short8*)(pr0);
  short8 ap1 = *(const short8*)(pr1);
  short8 v0 = *(const short8*)(vb);
  for (int kt = 0; kt < nkt; kt++) {
    short8 a0N, a1N, v0N;
    if (kt + 1 < nkt) {
      a0N = *(const short8*)(pr0 + (kt + 1) * 32);
      a1N = *(const short8*)(pr1 + (kt + 1) * 32);
      v0N = *(const short8*)(vb + (kt + 1) * 32);
    }
    __builtin_amdgcn_s_setprio(1);
    oa0 = __builtin_amdgcn_mfma_f32_16x16x32_bf16(ap0, v0, oa0, 0, 0, 0);
    oa1 = __builtin_amdgcn_mfma_f32_16x16x32_bf16(ap1, v0, oa1, 0, 0, 0);
    __builtin_amdgcn_s_setprio(0);
    ap0 = a0N; ap1 = a1N; v0 = v0N;
  }
  // stage O in LDS (reuse S), then store full 128B lines cooperatively
  __syncthreads();
  for (int r = 0; r < 4; r++) {
    S[(q * 4 + r) * 72 + w * 16 + lane15] = f2bt(oa0[r]);
    S[(16 + q * 4 + r) * 72 + w * 16 + lane15] = f2bt(oa1[r]);
  }
  __syncthreads();
  {
    int row = tid >> 3, c8 = tid & 7;
    ushort8 val = *(const ushort8*)(S + row * 72 + c8 * 8);
    *(ushort8*)(o + (base + p * 32 + row) * 512 + h * 64 + c8 * 8) = val;
  }
}

// ---------------------------------------------------------------------------
// k_ln: layernorm over D=512 per token, bf16 in/out. 4 rows per block.
// gamma/beta pre-converted to fp32 (lnAll) -> float4 loads (R10).
// ---------------------------------------------------------------------------
__global__ void k_ln(const unsigned short* __restrict__ x,
                     const float* __restrict__ gb,
                     unsigned short* __restrict__ out) {
  int row = blockIdx.x * 4 + (threadIdx.x >> 6);
  int lane = threadIdx.x & 63;
  ushort8 u = *(const ushort8*)(x + (size_t)row * D + lane * 8);
  float v[8]; float s = 0.f, s2 = 0.f;
#pragma unroll
  for (int t = 0; t < 8; t++) {
    v[t] = b2f(u[t]); s += v[t]; s2 += v[t] * v[t];
  }
  for (int off = 32; off; off >>= 1) {
    s += __shfl_xor(s, off); s2 += __shfl_xor(s2, off);
  }
  float m = s / (float)D;
  float inv = rsqrtf(s2 / (float)D - m * m + 1e-5f);
  float4v g0 = *(const float4v*)(gb + lane * 8);
  float4v g1v = *(const float4v*)(gb + lane * 8 + 4);
  float4v b0 = *(const float4v*)(gb + 512 + lane * 8);
  float4v b1v = *(const float4v*)(gb + 512 + lane * 8 + 4);
  float g[8] = {g0[0], g0[1], g0[2], g0[3], g1v[0], g1v[1], g1v[2], g1v[3]};
  float bb[8] = {b0[0], b0[1], b0[2], b0[3], b1v[0], b1v[1], b1v[2], b1v[3]};
  ushort8 ou;
#pragma unroll
  for (int t = 0; t < 8; t++) {
    ou[t] = f2b((v[t] - m) * inv * g[t] + bb[t]);
  }
  *(ushort8*)(out + (size_t)row * D + lane * 8) = ou;
}

// ---------------------------------------------------------------------------
// k_lnloss: fused final LN + recon head (MFMA) + masked MSE.
// ---------------------------------------------------------------------------
__global__ __launch_bounds__(128) void k_lnloss(
    const unsigned short* __restrict__ tok, const float* __restrict__ lnw,
    const unsigned short* __restrict__ WpT, const float* __restrict__ patches,
    const float* __restrict__ stdev, const int* __restrict__ mask_i,
    float* scal) {
  constexpr int RS = 520;  // padded LDS row stride (elements)
  __shared__ __align__(16) unsigned short As[32 * RS];
  __shared__ __align__(16) unsigned short Bs[16 * RS];
  int bpI = blockIdx.x; int b = bpI >> 6, p = bpI & 63;
  int tid = threadIdx.x;
  int row = tid >> 2, cg = tid & 3;   // 4 threads per token row
  size_t tokbase = (size_t)(b * L + p * 32);
  float s = 0.f, s2 = 0.f;
  for (int i = 0; i < 16; i++) {
    int c = cg + i * 4;
    ushort8 u = *(const ushort8*)(tok + (tokbase + row) * D + c * 8);
    for (int t = 0; t < 8; t++) { float v = b2f(u[t]); s += v; s2 += v * v; }
  }
  s += __shfl_xor(s, 1); s += __shfl_xor(s, 2);
  s2 += __shfl_xor(s2, 1); s2 += __shfl_xor(s2, 2);
  float m = s / (float)D;
  float inv = rsqrtf(s2 / (float)D - m * m + 1e-5f);
  for (int i = 0; i < 16; i++) {
    int c = cg + i * 4;
    ushort8 u = *(const ushort8*)(tok + (tokbase + row) * D + c * 8);
    ushort8 o;
    for (int t = 0; t < 8; t++) {
      int col = c * 8 + t;
      o[t] = f2b((b2f(u[t]) - m) * inv * lnw[col] + lnw[512 + col]);
    }
    *(ushort8*)(As + row * RS + c * 8) = o;
  }
  for (int e = tid; e < 16 * 64; e += 128) {
    int r = e >> 6, c = e & 63;
    *(ushort8*)(Bs + r * RS + c * 8) = *(const ushort8*)(WpT + r * 512 + c * 8);
  }
  __syncthreads();
  int w = tid >> 6, lane = tid & 63, lane15 = lane & 15, q = lane >> 4;
  float4v acc = 0;
  for (int kt = 0; kt < 16; kt++) {
    short8 a = *(const short8*)(As + (w * 16 + lane15) * RS + kt * 32 + q * 8);
    short8 bfr = *(const short8*)(Bs + lane15 * RS + kt * 32 + q * 8);
    acc = __builtin_amdgcn_mfma_f32_16x16x32_bf16(a, bfr, acc, 0, 0, 0);
  }
  float local = 0.f;
  int t = lane15;
  for (int r = 0; r < 4; r++) {
    int v = w * 16 + q * 4 + r;
    int tokidx = b * 2048 + p * 32 + v;
    if (mask_i[tokidx]) {
      float recon = acc[r] + lnw[1024 + t];
      float diff = recon - patches[(size_t)tokidx * 16 + t];
      float sc = stdev[b * 32 + v];
      local += sc * sc * diff * diff;
    }
  }
  for (int off = 32; off; off >>= 1) local += __shfl_xor(local, off);
  if (lane == 0) atomicAdd(&scal[0], local);
}

__global__ void k_final(const float* scal, const int* flags, unsigned* out) {
  float denom = (float)flags[1] * (float)PL;
  if (denom == 0.f) denom = 1.f;
  float loss = scal[0] / denom;
  unsigned fb = __float_as_uint(loss);
  unsigned u = (fb + 0x7FFFu + ((fb >> 16) & 1u)) >> 16;
  out[0] = (u << 16) | u;
}

}  // namespace

extern "C" void kernel_launch(void* const* d_in, const int* in_sizes, int n_in,
                              void* d_out, int out_size, void* d_ws,
                              size_t ws_size, hipStream_t stream) {
  const void* x_enc = d_in[0];
  const void* maskp = d_in[1];
  const void* We = d_in[2];  const void* be_ = d_in[3];
  const void* Wq = d_in[4];  const void* bq = d_in[5];
  const void* Wk = d_in[6];  const void* bk = d_in[7];
  const void* Wv = d_in[8];  const void* bv = d_in[9];
  const void* Wo = d_in[10]; const void* bo_ = d_in[11];
  const void* W1 = d_in[12]; const void* b1 = d_in[13];
  const void* W2 = d_in[14]; const void* b2 = d_in[15];
  const void* g1 = d_in[16]; const void* be1 = d_in[17];
  const void* g2 = d_in[18]; const void* be2 = d_in[19];
  const void* gf = d_in[20]; const void* bff = d_in[21];
  const void* Wp = d_in[22]; const void* bp = d_in[23];

  constexpr size_t MB = 1u << 20;
  char* w = (char*)d_ws;
  int*   mask_i  = (int*)w;                        // 32 KB
  int*   flags   = (int*)(w + 32768);
  float* scal    = (float*)(w + 32896);
  float* means   = (float*)(w + 33024);
  float* stdev   = (float*)(w + 33600);
  float* biasf   = (float*)(w + 36864);            // 73728 B -> ends 110592
  float* lnw     = (float*)(w + 114688);           // 4160 B
  float* patches = (float*)(w + 131072);           // 512 KB -> ends 655360
  unsigned short* WpT = (unsigned short*)(w + 655360);    // 16 KB -> 671744
  float* lnAllF  = (float*)(w + 688128);           // 32 KB -> ends 720896
  unsigned short* qkvT = (unsigned short*)(w + 1 * MB);   // 6 MB
  unsigned short* WoT  = (unsigned short*)(w + 7 * MB);   // 2 MB
  unsigned short* W1T  = (unsigned short*)(w + 9 * MB);   // 8 MB
  unsigned short* W2T  = (unsigned short*)(w + 17 * MB);  // 8 MB
  unsigned short* tok  = (unsigned short*)(w + 25 * MB);  // 8 MB
  unsigned short* tmp  = (unsigned short*)(w + 33 * MB);  // 8 MB
  unsigned short* ob   = (unsigned short*)(w + 41 * MB);  // 8 MB
  unsigned short* qk   = (unsigned short*)(w + 49 * MB);  // 16 MB -> ends 65
  unsigned short* vTb  = (unsigned short*)(w + 73 * MB);  // 8 MB -> ends 81
  unsigned short* hidden = ob;   // 32 MB alias over ob+qk (dead by FFN1)

  k_setup<<<1, 256, 0, stream>>>(gf, maskp, mask_i, flags, scal);
  k_prep<<<173, 256, 0, stream>>>(x_enc, bq, bk, bv, bo_, b1, b2, gf, bff, Wp,
                                  bp, g1, be1, g2, be2, flags, means, stdev,
                                  biasf, lnw, WpT, lnAllF);
  k_transpose_all<<<12288, 256, 0, stream>>>(Wq, Wk, Wv, Wo, W1, W2, qkvT, WoT,
                                             W1T, W2T, flags);
  k_embed<<<Bn * P, 512, 0, stream>>>(x_enc, We, be_, flags, mask_i, means,
                                      stdev, patches, tok);
  for (int l = 0; l < 4; l++) {
    // QKV: M=8192, N=1536, K=512 -> wide <128,128,64>, MW=1 (unclamped)
    k_gemm<128, 128, 64, 1><<<768, 256, 0, stream>>>(
        tok, qkvT + (size_t)l * 786432, biasf + l * 1536, nullptr, qk, vTb,
        1024, 512, 0, 12);
    k_attn<<<2048, 256, 0, stream>>>(qk, vTb, ob);
    // Wo: N=512, K=512 -> skinny <64,64,16>, MW=3 (R11 occupancy win)
    k_gemm<64, 64, 16, 3><<<1024, 256, 0, stream>>>(
        ob, WoT + (size_t)l * 262144, biasf + 6144 + l * 512, tok, tmp,
        nullptr, 512, 512, 0, 8);
    k_ln<<<M / 4, 256, 0, stream>>>(tmp, lnAllF + (size_t)(l * 2) * 1024, tok);
    // FFN1: M=8192, N=2048, K=512 -> wide <128,128,64>, MW=1
    k_gemm<128, 128, 64, 1><<<1024, 256, 0, stream>>>(
        tok, W1T + (size_t)l * 1048576, biasf + 8192 + l * 2048, nullptr,
        hidden, nullptr, 2048, 512, 1, 16);
    // FFN2: N=512, K=2048 -> skinny <64,64,16>, MW=3
    k_gemm<64, 64, 16, 3><<<1024, 256, 0, stream>>>(
        hidden, W2T + (size_t)l * 1048576, biasf + 16384 + l * 512, tok, tmp,
        nullptr, 512, 2048, 0, 8);
    k_ln<<<M / 4, 256, 0, stream>>>(tmp, lnAllF + (size_t)(l * 2 + 1) * 1024,
                                    tok);
  }
  k_lnloss<<<Bn * P, 128, 0, stream>>>(tok, lnw, WpT, patches, stdev, mask_i,
                                       scal);
  k_final<<<1, 1, 0, stream>>>(scal, flags, (unsigned*)d_out);
}

// Round 14
// 732.314 us; speedup vs baseline: 1.0458x; 1.0458x over previous
//
#include <hip/hip_runtime.h>
#include <hip/hip_bf16.h>

#define DEV __device__ __forceinline__

namespace {

constexpr int Bn  = 4, SEQ = 1024, NV = 32, PL = 16, D = 512, H = 8, DFF = 2048;
constexpr int P   = SEQ / PL;    // 64 patches
constexpr int L   = P * NV;      // 2048 tokens per batch
constexpr int M   = Bn * L;      // 8192 total token rows
constexpr int WIN = 4;

using short8   = __attribute__((ext_vector_type(8))) short;
using ushort8  = __attribute__((ext_vector_type(8))) unsigned short;
using ushort4  = __attribute__((ext_vector_type(4))) unsigned short;
using float4v  = __attribute__((ext_vector_type(4))) float;

DEV float b2f(unsigned short u) { return __uint_as_float(((unsigned)u) << 16); }
DEV unsigned short f2b(float f) {   // RNE (used where bias matters)
  unsigned fb = __float_as_uint(f);
  return (unsigned short)((fb + 0x7FFFu + ((fb >> 16) & 1u)) >> 16);
}
DEV unsigned short f2bt(float f) {  // truncation: 1 VALU op
  return (unsigned short)(__float_as_uint(f) >> 16);
}
// flag-dispatched float load from an input tensor: bf=1 -> bf16, 0 -> fp32
DEV float ldf(const void* p, size_t idx, int bf) {
  if (bf) return b2f(((const unsigned short*)p)[idx]);
  return ((const float*)p)[idx];
}
// async global->LDS 16B: lds dest = wave-uniform base + lane*16
DEV void gll16(const void* gp, void* lp) {
  __builtin_amdgcn_global_load_lds(
      (const __attribute__((address_space(1))) void*)gp,
      (__attribute__((address_space(3))) void*)lp, 16, 0, 0);
}

// ---------------------------------------------------------------------------
// k_setup: detect float dtype + mask format, canonicalize mask, count masked.
// ---------------------------------------------------------------------------
__global__ void k_setup(const void* gf, const void* mask_raw, int* mask_i,
                        int* flags, float* scal) {
  __shared__ int s_gt1, s_oth, s_cnt;
  int tid = threadIdx.x;
  if (tid == 0) { s_gt1 = 0; s_oth = 0; s_cnt = 0; }
  __syncthreads();
  const unsigned* mw = (const unsigned*)mask_raw;
  int gt1 = 0, oth = 0;
  for (int i = tid; i < 2048; i += 256) {
    unsigned w = mw[i];
    if (w > 1u) { gt1 = 1; if (w != 0x3F800000u) oth = 1; }
  }
  if (gt1) atomicOr(&s_gt1, 1);
  if (oth) atomicOr(&s_oth, 1);
  __syncthreads();
  int fmt = (!s_gt1) ? 0 : (!s_oth ? 1 : 2);  // 0=int32, 1=f32, 2=bytes
  int cnt = 0;
  for (int i = tid; i < Bn * P * NV; i += 256) {
    int m;
    if (fmt == 0)      m = ((const int*)mask_raw)[i] != 0;
    else if (fmt == 1) m = ((const float*)mask_raw)[i] != 0.0f;
    else               m = ((const unsigned char*)mask_raw)[i] != 0;
    mask_i[i] = m; cnt += m;
  }
  atomicAdd(&s_cnt, cnt);
  __syncthreads();
  if (tid == 0) {
    unsigned w = *(const unsigned*)gf;
    flags[0] = ((w & 0xFFFFu) == 0x3F80u) ? 1 : 0;
    flags[1] = s_cnt;
    scal[0] = 0.f;
  }
}

// ---------------------------------------------------------------------------
// k_prep: blocks 0..31 -> per-(b,v) stats; blocks 32.. -> gather biases,
// final-LN weights (fp32), b_proj (fp32), WpT (bf16 [t][d]), and ALL
// per-layer LN gamma/beta as fp32 (R10). lnAll: [l][phase][g:512|b:512].
// ---------------------------------------------------------------------------
__global__ void k_prep(const void* x, const void* bq, const void* bk,
                       const void* bv, const void* bo, const void* b1,
                       const void* b2, const void* gf, const void* bff,
                       const void* Wp, const void* bp, const void* g1,
                       const void* be1, const void* g2, const void* be2,
                       const int* flags, float* means, float* stdev,
                       float* biasf, float* lnw, unsigned short* WpT,
                       float* lnAll) {
  int bf = flags[0];
  int tid = threadIdx.x;
  if (blockIdx.x < 32) {
    int bv_ = blockIdx.x * 4 + (tid >> 6);
    int b = bv_ >> 5, v = bv_ & 31;
    int lane = tid & 63;
    float s = 0.f, s2 = 0.f;
    for (int t = lane; t < SEQ; t += 64) {
      float val = ldf(x, (size_t)b * SEQ * NV + (size_t)t * NV + v, bf);
      s += val; s2 += val * val;
    }
    for (int off = 32; off; off >>= 1) {
      s += __shfl_xor(s, off); s2 += __shfl_xor(s2, off);
    }
    if (lane == 0) {
      float m = s / (float)SEQ;
      means[bv_] = m;
      stdev[bv_] = sqrtf(s2 / (float)SEQ - m * m + 1e-5f);
    }
    return;
  }
  int i = (blockIdx.x - 32) * 256 + tid;
  if (i < 18432) {
    int l = i / 4608, r = i % 4608;
    if (r < 1536) {
      float v = (r < 512) ? ldf(bq, l * 512 + r, bf)
              : (r < 1024) ? ldf(bk, l * 512 + r - 512, bf)
                           : ldf(bv, l * 512 + r - 1024, bf);
      biasf[l * 1536 + r] = v;
    } else if (r < 2048) {
      biasf[6144 + l * 512 + (r - 1536)] = ldf(bo, l * 512 + r - 1536, bf);
    } else if (r < 4096) {
      biasf[8192 + l * 2048 + (r - 2048)] = ldf(b1, l * 2048 + r - 2048, bf);
    } else {
      biasf[16384 + l * 512 + (r - 4096)] = ldf(b2, l * 512 + r - 4096, bf);
    }
  } else if (i < 19456) {
    int j = i - 18432;
    lnw[j] = (j < 512) ? ldf(gf, j, bf) : ldf(bff, j - 512, bf);
  } else if (i < 19472) {
    lnw[1024 + (i - 19456)] = ldf(bp, i - 19456, bf);
  } else if (i < 27664) {
    int j = i - 19472; int t = j >> 9, d = j & 511;
    WpT[j] = f2b(ldf(Wp, d * 16 + t, bf));
  } else if (i < 35856) {
    int j = i - 27664;
    int l = j >> 11, r = j & 2047;
    int ph = r >> 10, c = r & 1023;
    const void* src = (c < 512) ? (ph ? g2 : g1) : (ph ? be2 : be1);
    lnAll[j] = ldf(src, l * 512 + (c & 511), bf);
  }
}

// ---------------------------------------------------------------------------
// k_transpose_all: all 6 weight transposes in one dispatch.
// dst[l][n][k] (bf16) = src[l][k][n]. 32x32 LDS tile per block.
// ---------------------------------------------------------------------------
__global__ void k_transpose_all(const void* Wq, const void* Wk, const void* Wv,
                                const void* Wo, const void* W1, const void* W2,
                                unsigned short* qkvT, unsigned short* WoT,
                                unsigned short* W1T, unsigned short* W2T,
                                const int* flags) {
  int bf = flags[0];
  int id = blockIdx.x;
  const void* src; unsigned short* dst;
  int Kd, Nd, l, n0, k0, dstOff = 0;
  size_t srcLS, dstLS;
  if (id < 4096) {
    int tensor = id >> 10, rem = id & 1023;
    l = rem >> 8; int t = rem & 255;
    n0 = (t & 15) * 32; k0 = (t >> 4) * 32;
    Kd = 512; Nd = 512; srcLS = 262144;
    if (tensor == 0)      { src = Wq; dst = qkvT; dstLS = 786432; dstOff = 0; }
    else if (tensor == 1) { src = Wk; dst = qkvT; dstLS = 786432; dstOff = 262144; }
    else if (tensor == 2) { src = Wv; dst = qkvT; dstLS = 786432; dstOff = 524288; }
    else                  { src = Wo; dst = WoT;  dstLS = 262144; }
  } else if (id < 8192) {
    int rem = id - 4096; l = rem >> 10; int t = rem & 1023;
    n0 = (t & 63) * 32; k0 = (t >> 6) * 32;
    Kd = 512; Nd = 2048; srcLS = 1048576; src = W1; dst = W1T; dstLS = 1048576;
  } else {
    int rem = id - 8192; l = rem >> 10; int t = rem & 1023;
    n0 = (t & 15) * 32; k0 = (t >> 4) * 32;
    Kd = 2048; Nd = 512; srcLS = 1048576; src = W2; dst = W2T; dstLS = 1048576;
  }
  int tx = threadIdx.x & 31, ty = threadIdx.x >> 5;
  __shared__ float tile[32][33];
  for (int rr = ty; rr < 32; rr += 8)
    tile[rr][tx] =
        ldf(src, (size_t)l * srcLS + (size_t)(k0 + rr) * Nd + n0 + tx, bf);
  __syncthreads();
  for (int rr = ty; rr < 32; rr += 8)
    dst[(size_t)l * dstLS + dstOff + (size_t)(n0 + rr) * Kd + k0 + tx] =
        f2b(tile[tx][rr]);
}

// ---------------------------------------------------------------------------
// k_embed (R11, kept): one block per (b,p) patch, 512 thr. We staged ONCE in
// LDS as float4 [t][d4] (32 KB). Thread (v = tid>>4, c = tid&15) computes
// token v, d4-set c+16k; ushort4 stores coalesce. Bit-identical math.
// ---------------------------------------------------------------------------
__global__ __launch_bounds__(512) void k_embed(
    const void* x, const void* We, const void* be, const int* flags,
    const int* mask_i, const float* means, const float* stdev,
    float* patches, unsigned short* tok) {
  int bp = blockIdx.x;              // Bn*P = 256 blocks
  int b = bp >> 6, p = bp & 63;
  int bf = flags[0];
  __shared__ float4v sWe[16 * 128];   // [t][d4], 32 KB
  __shared__ float4v sbe[128];
  __shared__ float spv[32][17];
  int tid = threadIdx.x;
  for (int i = tid; i < 2048; i += 512) {
    float4v w4;
    w4[0] = ldf(We, (size_t)i * 4 + 0, bf);
    w4[1] = ldf(We, (size_t)i * 4 + 1, bf);
    w4[2] = ldf(We, (size_t)i * 4 + 2, bf);
    w4[3] = ldf(We, (size_t)i * 4 + 3, bf);
    sWe[i] = w4;
  }
  if (tid < 128) {
    float4v b4;
    b4[0] = ldf(be, tid * 4 + 0, bf);
    b4[1] = ldf(be, tid * 4 + 1, bf);
    b4[2] = ldf(be, tid * 4 + 2, bf);
    b4[3] = ldf(be, tid * 4 + 3, bf);
    sbe[tid] = b4;
  }
  {
    int t = tid >> 5, v = tid & 31;
    float m = means[b * NV + v], sd = stdev[b * NV + v];
    float val =
        (ldf(x, (size_t)b * SEQ * NV + (size_t)(p * PL + t) * NV + v, bf) -
         m) / sd;
    spv[v][t] = val;
    patches[(size_t)((b << 11) + (p << 5) + v) * PL + t] = val;
  }
  __syncthreads();
  int v = tid >> 4, c = tid & 15;
  int idx = (b << 11) + (p << 5) + v;
  int masked = mask_i[idx];
  float pv[16];
#pragma unroll
  for (int t = 0; t < 16; t++) pv[t] = spv[v][t];
  unsigned short* orow = tok + (size_t)idx * D;
#pragma unroll
  for (int k = 0; k < 8; k++) {
    int d4 = c + (k << 4);
    float4v acc = sbe[d4];
#pragma unroll
    for (int t = 0; t < 16; t++) {
      float4v w4 = sWe[t * 128 + d4];
      acc[0] += pv[t] * w4[0];
      acc[1] += pv[t] * w4[1];
      acc[2] += pv[t] * w4[2];
      acc[3] += pv[t] * w4[3];
    }
    ushort4 ou;
    ou[0] = masked ? (unsigned short)0 : f2b(acc[0]);
    ou[1] = masked ? (unsigned short)0 : f2b(acc[1]);
    ou[2] = masked ? (unsigned short)0 : f2b(acc[2]);
    ou[3] = masked ? (unsigned short)0 : f2b(acc[3]);
    *(ushort4*)(orow + d4 * 4) = ou;
  }
}

// ---------------------------------------------------------------------------
// k_gemm<BM,BN,WN>: C = act(A @ W^T' + bias [+resid]) in bf16. BK=64.
// Linear grid, XCD-swizzled. Epilogue through LDS for coalesced ushort8 IO.
// R14: EXACT R11 reproduction — __launch_bounds__(256, 3) on the single
// template, all instantiations. Ledger across R10-R13 (only embed/bounds
// changed): R10 plain=767, R11 all-clamped=728, R12 plain=763, R13
// split=766. Embed rewrite alone = ~4 us (R10 vs R12), so R11's -35 vs
// plain came from clamping the WIDE tiles: per-block inner loop is slower
// (VGPR 56, bank conflicts, MfmaUtil 9) but NO scratch (WRITE = real
// output) and 3-blocks/CU residency wins NET. Skinny clamp = ~0 (R13).
// All constant-trip loops carry #pragma unroll (rule #20).
// ---------------------------------------------------------------------------
template <int BM, int BN, int WN>
__global__ __launch_bounds__(256, 3) void k_gemm(
    const unsigned short* __restrict__ A, const unsigned short* __restrict__ W,
    const float* __restrict__ bias, const unsigned short* __restrict__ resid,
    unsigned short* __restrict__ C, unsigned short* __restrict__ vTp, int cs,
    int Kk, int act, int nbn) {
  constexpr int FI = 4, FJ = WN / 16, NWN = BN / WN;
  __shared__ __align__(16) char sm[BM * 128 + BN * 128];
  char* As = sm;
  char* Bs = sm + BM * 128;
  unsigned short* Cl = (unsigned short*)sm;
  int tid = threadIdx.x, lane = tid & 63, w = tid >> 6;
  int lane15 = lane & 15, q = lane >> 4;
  int wm = w / NWN, wn = w % NWN;
  int id = blockIdx.x;
  int xcd = id & 7, loc = id >> 3;
  int bn = (loc % nbn) * BN;
  int bm = (xcd * ((int)(gridDim.x >> 3) / nbn) + loc / nbn) * BM;
  int lrow = lane >> 3, lc = lane & 7;
  float4v acc[FI][FJ];
#pragma unroll
  for (int i = 0; i < FI; i++)
#pragma unroll
    for (int j = 0; j < FJ; j++) acc[i][j] = 0;
  for (int k0 = 0; k0 < Kk; k0 += 64) {
    if (k0) __syncthreads();
    for (int i = w; i < BM / 8; i += 4) {
      int row = i * 8 + lrow;
      gll16(A + (size_t)(bm + row) * Kk + k0 + ((lc ^ (row & 7)) << 3),
            As + i * 1024);
    }
    for (int i = w; i < BN / 8; i += 4) {
      int row = i * 8 + lrow;
      gll16(W + (size_t)(bn + row) * Kk + k0 + ((lc ^ (row & 7)) << 3),
            Bs + i * 1024);
    }
    __syncthreads();
    short8 a[2][FI], b[2][FJ];
#pragma unroll
    for (int h = 0; h < 2; h++) {
#pragma unroll
      for (int i = 0; i < FI; i++) {
        int rr = wm * 64 + i * 16 + lane15;
        a[h][i] =
            *(const short8*)(As + rr * 128 + (((h * 4 + q) ^ (rr & 7)) << 4));
      }
#pragma unroll
      for (int j = 0; j < FJ; j++) {
        int rr = wn * WN + j * 16 + lane15;
        b[h][j] =
            *(const short8*)(Bs + rr * 128 + (((h * 4 + q) ^ (rr & 7)) << 4));
      }
    }
#pragma unroll
    for (int h = 0; h < 2; h++)
#pragma unroll
      for (int i = 0; i < FI; i++)
#pragma unroll
        for (int j = 0; j < FJ; j++)
          acc[i][j] = __builtin_amdgcn_mfma_f32_16x16x32_bf16(
              a[h][i], b[h][j], acc[i][j], 0, 0, 0);
  }
  // ---- epilogue through LDS ----
  int vmode = (vTp != nullptr) && (bn >= 1024);
  float oscale = (vTp != nullptr && bn < 512) ? 0.125f : 1.0f;  // q pre-scale
  __syncthreads();  // all MFMAs done reading As/Bs
#pragma unroll
  for (int i = 0; i < FI; i++) {
#pragma unroll
    for (int j = 0; j < FJ; j++) {
      int col = wn * WN + j * 16 + lane15;        // tile-local col
      float bv = bias[bn + col];
#pragma unroll
      for (int r = 0; r < 4; r++) {
        int row = wm * 64 + i * 16 + q * 4 + r;   // tile-local row
        float cv = (acc[i][j][r] + bv) * oscale;
        if (act) {  // fast GELU: x * sigmoid(1.5958x + 0.07135x^3)
          float t = cv * (1.5957692f + 0.0713548f * cv * cv);
          cv = cv / (1.f + __expf(-t));
        }
        if (!vmode)
          Cl[row * BN + (((col >> 3) ^ (row & 7)) << 3) + (col & 7)] = f2bt(cv);
        else
          Cl[col * BM + (((row >> 3) ^ (col & 7)) << 3) + (row & 7)] = f2bt(cv);
      }
    }
  }
  __syncthreads();
  if (!vmode) {
    constexpr int TOT = BM * BN / 8;
    for (int e = tid; e < TOT; e += 256) {
      int rr = e / (BN / 8), c8 = e % (BN / 8);
      ushort8 u = *(const ushort8*)(Cl + rr * BN + ((c8 ^ (rr & 7)) << 3));
      size_t off = (size_t)(bm + rr) * cs + bn + c8 * 8;
      if (resid) {
        ushort8 rv = *(const ushort8*)(resid + off);
#pragma unroll
        for (int t = 0; t < 8; t++) u[t] = f2bt(b2f(u[t]) + b2f(rv[t]));
      }
      *(ushort8*)(C + off) = u;
    }
  } else {
    constexpr int TOT = BM * BN / 8;
    for (int e = tid; e < TOT; e += 256) {
      int cc = e / (BM / 8), t8 = e % (BM / 8);
      ushort8 u = *(const ushort8*)(Cl + cc * BM + ((t8 ^ (cc & 7)) << 3));
      int hd = bn - 1024 + cc;
      int rowg = bm + t8 * 8;
      int bb = rowg >> 11, tokin = rowg & 2047;
      *(ushort8*)(vTp + ((size_t)(bb * 512 + hd)) * 2048 + tokin) = u;
    }
  }
}

// ---------------------------------------------------------------------------
// k_attn: banded MFMA attention, fragment-direct global loads. 19.5 KB LDS,
// VGPR <64 -> 8 blocks/CU. q pre-scaled by 0.125 in QKV GEMM; softmax skips
// max-sub (|s| <~ 5). T5 s_setprio(1) around MFMA clusters (R10 win).
// ---------------------------------------------------------------------------
__global__ __launch_bounds__(256) void k_attn(
    const unsigned short* __restrict__ qk,
    const unsigned short* __restrict__ vT, unsigned short* __restrict__ o) {
  constexpr int SSTR = 304;
  __shared__ __align__(16) unsigned short S[32 * SSTR];
  int id = blockIdx.x;
  int xcd = id & 7, rr_ = id >> 3;
  int p = xcd * 8 + (rr_ & 7);
  int h = (rr_ >> 3) & 7;
  int b = rr_ >> 6;
  int tid = threadIdx.x, lane = tid & 63, w = tid >> 6;
  int lane15 = lane & 15, q = lane >> 4;
  int p0 = max(0, p - WIN), p1 = min(P - 1, p + WIN);
  int nk = (p1 - p0 + 1) * 32;     // multiple of 32, in [160,288]
  int ntiles = nk >> 4;
  size_t base = (size_t)b * L;
  // Q fragments for BOTH m-tiles (A-operand), direct global
  short8 aq[2][2];
  for (int m = 0; m < 2; m++) {
    const unsigned short* qrow =
        qk + (base + p * 32 + m * 16 + lane15) * 1024 + h * 64 + q * 8;
    aq[m][0] = *(const short8*)(qrow);
    aq[m][1] = *(const short8*)(qrow + 32);
  }
  const unsigned short* kbase =
      qk + (base + p0 * 32) * 1024 + 512 + h * 64 + q * 8;
  // phase A: wave w handles nt = w, w+4, ... (no duplicate K loads)
  {
    int nt = w;
    const unsigned short* kr = kbase + (size_t)(nt * 16 + lane15) * 1024;
    short8 c0, c1, n0, n1;
    if (nt < ntiles) {
      c0 = *(const short8*)(kr);
      c1 = *(const short8*)(kr + 32);
    }
    if (nt + 4 < ntiles) {
      kr = kbase + (size_t)((nt + 4) * 16 + lane15) * 1024;
      n0 = *(const short8*)(kr);
      n1 = *(const short8*)(kr + 32);
    }
    for (; nt < ntiles; nt += 4) {
      short8 m0, m1;
      if (nt + 8 < ntiles) {
        kr = kbase + (size_t)((nt + 8) * 16 + lane15) * 1024;
        m0 = *(const short8*)(kr);
        m1 = *(const short8*)(kr + 32);
      }
      __builtin_amdgcn_s_setprio(1);
      for (int m = 0; m < 2; m++) {
        float4v s4 = 0;
        s4 = __builtin_amdgcn_mfma_f32_16x16x32_bf16(aq[m][0], c0, s4, 0, 0, 0);
        s4 = __builtin_amdgcn_mfma_f32_16x16x32_bf16(aq[m][1], c1, s4, 0, 0, 0);
        for (int r = 0; r < 4; r++)
          S[(m * 16 + q * 4 + r) * SSTR + nt * 16 + lane15] = f2b(s4[r]);
      }
      __builtin_amdgcn_s_setprio(0);
      c0 = n0; c1 = n1; n0 = m0; n1 = m1;
    }
  }
  __syncthreads();
  // phase B: softmax without max-sub, b128 LDS IO, trunc P pack
  {
    int row = tid >> 3, c = tid & 7;
    ushort8 eb[5];
    float sum = 0.f;
    for (int k = 0; k < 5; k++) {
      int j0 = c * 8 + k * 64;
      if (j0 < nk) {
        ushort8 u = *(const ushort8*)(S + row * SSTR + j0);
        ushort8 e8;
        for (int t = 0; t < 8; t++) {
          float e = __expf(b2f(u[t]));
          sum += e;
          e8[t] = f2bt(e);
        }
        eb[k] = e8;
      }
    }
    for (int off = 1; off < 8; off <<= 1) sum += __shfl_xor(sum, off);
    float inv = 1.f / sum;
    for (int k = 0; k < 5; k++) {
      int j0 = c * 8 + k * 64;
      if (j0 < nk) {
        ushort8 e8 = eb[k], u;
        for (int t = 0; t < 8; t++) u[t] = f2bt(b2f(e8[t]) * inv);
        *(ushort8*)(S + row * SSTR + j0) = u;
      }
    }
  }
  __syncthreads();
  // phase C: O = P V. Wave w owns column tile w (16 cols), both m-tiles --
  // one V load per kt feeds 2 MFMAs (no duplicate V loads across waves).
  int nkt = nk >> 5;
  const unsigned short* vb =
      vT + (size_t)(b * 512 + h * 64 + w * 16 + lane15) * 2048 + p0 * 32 +
      q * 8;
  const unsigned short* pr0 = S + lane15 * SSTR + q * 8;
  const unsigned short* pr1 = S + (16 + lane15) * SSTR + q * 8;
  float4v oa0 = 0, oa1 = 0;
  short8 ap0 = *(const short8*)(pr0);
  short8 ap1 = *(const short8*)(pr1);
  short8 v0 = *(const short8*)(vb);
  for (int kt = 0; kt < nkt; kt++) {
    short8 a0N, a1N, v0N;
    if (kt + 1 < nkt) {
      a0N = *(const short8*)(pr0 + (kt + 1) * 32);
      a1N = *(const short8*)(pr1 + (kt + 1) * 32);
      v0N = *(const short8*)(vb + (kt + 1) * 32);
    }
    __builtin_amdgcn_s_setprio(1);
    oa0 = __builtin_amdgcn_mfma_f32_16x16x32_bf16(ap0, v0, oa0, 0, 0, 0);
    oa1 = __builtin_amdgcn_mfma_f32_16x16x32_bf16(ap1, v0, oa1, 0, 0, 0);
    __builtin_amdgcn_s_setprio(0);
    ap0 = a0N; ap1 = a1N; v0 = v0N;
  }
  // stage O in LDS (reuse S), then store full 128B lines cooperatively
  __syncthreads();
  for (int r = 0; r < 4; r++) {
    S[(q * 4 + r) * 72 + w * 16 + lane15] = f2bt(oa0[r]);
    S[(16 + q * 4 + r) * 72 + w * 16 + lane15] = f2bt(oa1[r]);
  }
  __syncthreads();
  {
    int row = tid >> 3, c8 = tid & 7;
    ushort8 val = *(const ushort8*)(S + row * 72 + c8 * 8);
    *(ushort8*)(o + (base + p * 32 + row) * 512 + h * 64 + c8 * 8) = val;
  }
}

// ---------------------------------------------------------------------------
// k_ln: layernorm over D=512 per token, bf16 in/out. 4 rows per block.
// gamma/beta pre-converted to fp32 (lnAll) -> float4 loads (R10).
// ---------------------------------------------------------------------------
__global__ void k_ln(const unsigned short* __restrict__ x,
                     const float* __restrict__ gb,
                     unsigned short* __restrict__ out) {
  int row = blockIdx.x * 4 + (threadIdx.x >> 6);
  int lane = threadIdx.x & 63;
  ushort8 u = *(const ushort8*)(x + (size_t)row * D + lane * 8);
  float v[8]; float s = 0.f, s2 = 0.f;
#pragma unroll
  for (int t = 0; t < 8; t++) {
    v[t] = b2f(u[t]); s += v[t]; s2 += v[t] * v[t];
  }
  for (int off = 32; off; off >>= 1) {
    s += __shfl_xor(s, off); s2 += __shfl_xor(s2, off);
  }
  float m = s / (float)D;
  float inv = rsqrtf(s2 / (float)D - m * m + 1e-5f);
  float4v g0 = *(const float4v*)(gb + lane * 8);
  float4v g1v = *(const float4v*)(gb + lane * 8 + 4);
  float4v b0 = *(const float4v*)(gb + 512 + lane * 8);
  float4v b1v = *(const float4v*)(gb + 512 + lane * 8 + 4);
  float g[8] = {g0[0], g0[1], g0[2], g0[3], g1v[0], g1v[1], g1v[2], g1v[3]};
  float bb[8] = {b0[0], b0[1], b0[2], b0[3], b1v[0], b1v[1], b1v[2], b1v[3]};
  ushort8 ou;
#pragma unroll
  for (int t = 0; t < 8; t++) {
    ou[t] = f2b((v[t] - m) * inv * g[t] + bb[t]);
  }
  *(ushort8*)(out + (size_t)row * D + lane * 8) = ou;
}

// ---------------------------------------------------------------------------
// k_lnloss: fused final LN + recon head (MFMA) + masked MSE.
// ---------------------------------------------------------------------------
__global__ __launch_bounds__(128) void k_lnloss(
    const unsigned short* __restrict__ tok, const float* __restrict__ lnw,
    const unsigned short* __restrict__ WpT, const float* __restrict__ patches,
    const float* __restrict__ stdev, const int* __restrict__ mask_i,
    float* scal) {
  constexpr int RS = 520;  // padded LDS row stride (elements)
  __shared__ __align__(16) unsigned short As[32 * RS];
  __shared__ __align__(16) unsigned short Bs[16 * RS];
  int bpI = blockIdx.x; int b = bpI >> 6, p = bpI & 63;
  int tid = threadIdx.x;
  int row = tid >> 2, cg = tid & 3;   // 4 threads per token row
  size_t tokbase = (size_t)(b * L + p * 32);
  float s = 0.f, s2 = 0.f;
  for (int i = 0; i < 16; i++) {
    int c = cg + i * 4;
    ushort8 u = *(const ushort8*)(tok + (tokbase + row) * D + c * 8);
    for (int t = 0; t < 8; t++) { float v = b2f(u[t]); s += v; s2 += v * v; }
  }
  s += __shfl_xor(s, 1); s += __shfl_xor(s, 2);
  s2 += __shfl_xor(s2, 1); s2 += __shfl_xor(s2, 2);
  float m = s / (float)D;
  float inv = rsqrtf(s2 / (float)D - m * m + 1e-5f);
  for (int i = 0; i < 16; i++) {
    int c = cg + i * 4;
    ushort8 u = *(const ushort8*)(tok + (tokbase + row) * D + c * 8);
    ushort8 o;
    for (int t = 0; t < 8; t++) {
      int col = c * 8 + t;
      o[t] = f2b((b2f(u[t]) - m) * inv * lnw[col] + lnw[512 + col]);
    }
    *(ushort8*)(As + row * RS + c * 8) = o;
  }
  for (int e = tid; e < 16 * 64; e += 128) {
    int r = e >> 6, c = e & 63;
    *(ushort8*)(Bs + r * RS + c * 8) = *(const ushort8*)(WpT + r * 512 + c * 8);
  }
  __syncthreads();
  int w = tid >> 6, lane = tid & 63, lane15 = lane & 15, q = lane >> 4;
  float4v acc = 0;
  for (int kt = 0; kt < 16; kt++) {
    short8 a = *(const short8*)(As + (w * 16 + lane15) * RS + kt * 32 + q * 8);
    short8 bfr = *(const short8*)(Bs + lane15 * RS + kt * 32 + q * 8);
    acc = __builtin_amdgcn_mfma_f32_16x16x32_bf16(a, bfr, acc, 0, 0, 0);
  }
  float local = 0.f;
  int t = lane15;
  for (int r = 0; r < 4; r++) {
    int v = w * 16 + q * 4 + r;
    int tokidx = b * 2048 + p * 32 + v;
    if (mask_i[tokidx]) {
      float recon = acc[r] + lnw[1024 + t];
      float diff = recon - patches[(size_t)tokidx * 16 + t];
      float sc = stdev[b * 32 + v];
      local += sc * sc * diff * diff;
    }
  }
  for (int off = 32; off; off >>= 1) local += __shfl_xor(local, off);
  if (lane == 0) atomicAdd(&scal[0], local);
}

__global__ void k_final(const float* scal, const int* flags, unsigned* out) {
  float denom = (float)flags[1] * (float)PL;
  if (denom == 0.f) denom = 1.f;
  float loss = scal[0] / denom;
  unsigned fb = __float_as_uint(loss);
  unsigned u = (fb + 0x7FFFu + ((fb >> 16) & 1u)) >> 16;
  out[0] = (u << 16) | u;
}

}  // namespace

extern "C" void kernel_launch(void* const* d_in, const int* in_sizes, int n_in,
                              void* d_out, int out_size, void* d_ws,
                              size_t ws_size, hipStream_t stream) {
  const void* x_enc = d_in[0];
  const void* maskp = d_in[1];
  const void* We = d_in[2];  const void* be_ = d_in[3];
  const void* Wq = d_in[4];  const void* bq = d_in[5];
  const void* Wk = d_in[6];  const void* bk = d_in[7];
  const void* Wv = d_in[8];  const void* bv = d_in[9];
  const void* Wo = d_in[10]; const void* bo_ = d_in[11];
  const void* W1 = d_in[12]; const void* b1 = d_in[13];
  const void* W2 = d_in[14]; const void* b2 = d_in[15];
  const void* g1 = d_in[16]; const void* be1 = d_in[17];
  const void* g2 = d_in[18]; const void* be2 = d_in[19];
  const void* gf = d_in[20]; const void* bff = d_in[21];
  const void* Wp = d_in[22]; const void* bp = d_in[23];

  constexpr size_t MB = 1u << 20;
  char* w = (char*)d_ws;
  int*   mask_i  = (int*)w;                        // 32 KB
  int*   flags   = (int*)(w + 32768);
  float* scal    = (float*)(w + 32896);
  float* means   = (float*)(w + 33024);
  float* stdev   = (float*)(w + 33600);
  float* biasf   = (float*)(w + 36864);            // 73728 B -> ends 110592
  float* lnw     = (float*)(w + 114688);           // 4160 B
  float* patches = (float*)(w + 131072);           // 512 KB -> ends 655360
  unsigned short* WpT = (unsigned short*)(w + 655360);    // 16 KB -> 671744
  float* lnAllF  = (float*)(w + 688128);           // 32 KB -> ends 720896
  unsigned short* qkvT = (unsigned short*)(w + 1 * MB);   // 6 MB
  unsigned short* WoT  = (unsigned short*)(w + 7 * MB);   // 2 MB
  unsigned short* W1T  = (unsigned short*)(w + 9 * MB);   // 8 MB
  unsigned short* W2T  = (unsigned short*)(w + 17 * MB);  // 8 MB
  unsigned short* tok  = (unsigned short*)(w + 25 * MB);  // 8 MB
  unsigned short* tmp  = (unsigned short*)(w + 33 * MB);  // 8 MB
  unsigned short* ob   = (unsigned short*)(w + 41 * MB);  // 8 MB
  unsigned short* qk   = (unsigned short*)(w + 49 * MB);  // 16 MB -> ends 65
  unsigned short* vTb  = (unsigned short*)(w + 73 * MB);  // 8 MB -> ends 81
  unsigned short* hidden = ob;   // 32 MB alias over ob+qk (dead by FFN1)

  k_setup<<<1, 256, 0, stream>>>(gf, maskp, mask_i, flags, scal);
  k_prep<<<173, 256, 0, stream>>>(x_enc, bq, bk, bv, bo_, b1, b2, gf, bff, Wp,
                                  bp, g1, be1, g2, be2, flags, means, stdev,
                                  biasf, lnw, WpT, lnAllF);
  k_transpose_all<<<12288, 256, 0, stream>>>(Wq, Wk, Wv, Wo, W1, W2, qkvT, WoT,
                                             W1T, W2T, flags);
  k_embed<<<Bn * P, 512, 0, stream>>>(x_enc, We, be_, flags, mask_i, means,
                                      stdev, patches, tok);
  for (int l = 0; l < 4; l++) {
    // QKV: M=8192, N=1536, K=512 -> <128,128,64>, grid 768
    k_gemm<128, 128, 64><<<768, 256, 0, stream>>>(
        tok, qkvT + (size_t)l * 786432, biasf + l * 1536, nullptr, qk, vTb,
        1024, 512, 0, 12);
    k_attn<<<2048, 256, 0, stream>>>(qk, vTb, ob);
    // Wo: N=512, K=512 -> skinny <64,64,16> @1024 blocks
    k_gemm<64, 64, 16><<<1024, 256, 0, stream>>>(
        ob, WoT + (size_t)l * 262144, biasf + 6144 + l * 512, tok, tmp,
        nullptr, 512, 512, 0, 8);
    k_ln<<<M / 4, 256, 0, stream>>>(tmp, lnAllF + (size_t)(l * 2) * 1024, tok);
    // FFN1: M=8192, N=2048, K=512 -> <128,128,64>, grid 1024
    k_gemm<128, 128, 64><<<1024, 256, 0, stream>>>(
        tok, W1T + (size_t)l * 1048576, biasf + 8192 + l * 2048, nullptr,
        hidden, nullptr, 2048, 512, 1, 16);
    // FFN2: N=512, K=2048 -> skinny <64,64,16> @1024
    k_gemm<64, 64, 16><<<1024, 256, 0, stream>>>(
        hidden, W2T + (size_t)l * 1048576, biasf + 16384 + l * 512, tok, tmp,
        nullptr, 512, 2048, 0, 8);
    k_ln<<<M / 4, 256, 0, stream>>>(tmp, lnAllF + (size_t)(l * 2 + 1) * 1024,
                                    tok);
  }
  k_lnloss<<<Bn * P, 128, 0, stream>>>(tok, lnw, WpT, patches, stdev, mask_i,
                                       scal);
  k_final<<<1, 1, 0, stream>>>(scal, flags, (unsigned*)d_out);
}

// Round 15
// 725.654 us; speedup vs baseline: 1.0554x; 1.0092x over previous
//
#include <hip/hip_runtime.h>
#include <hip/hip_bf16.h>

#define DEV __device__ __forceinline__

namespace {

constexpr int Bn  = 4, SEQ = 1024, NV = 32, PL = 16, D = 512, H = 8, DFF = 2048;
constexpr int P   = SEQ / PL;    // 64 patches
constexpr int L   = P * NV;      // 2048 tokens per batch
constexpr int M   = Bn * L;      // 8192 total token rows
constexpr int WIN = 4;

using short8   = __attribute__((ext_vector_type(8))) short;
using ushort8  = __attribute__((ext_vector_type(8))) unsigned short;
using ushort4  = __attribute__((ext_vector_type(4))) unsigned short;
using float4v  = __attribute__((ext_vector_type(4))) float;

DEV float b2f(unsigned short u) { return __uint_as_float(((unsigned)u) << 16); }
DEV unsigned short f2b(float f) {   // RNE (used where bias matters)
  unsigned fb = __float_as_uint(f);
  return (unsigned short)((fb + 0x7FFFu + ((fb >> 16) & 1u)) >> 16);
}
DEV unsigned short f2bt(float f) {  // truncation: 1 VALU op
  return (unsigned short)(__float_as_uint(f) >> 16);
}
// flag-dispatched float load from an input tensor: bf=1 -> bf16, 0 -> fp32
DEV float ldf(const void* p, size_t idx, int bf) {
  if (bf) return b2f(((const unsigned short*)p)[idx]);
  return ((const float*)p)[idx];
}
// async global->LDS 16B: lds dest = wave-uniform base + lane*16
DEV void gll16(const void* gp, void* lp) {
  __builtin_amdgcn_global_load_lds(
      (const __attribute__((address_space(1))) void*)gp,
      (__attribute__((address_space(3))) void*)lp, 16, 0, 0);
}

// ---------------------------------------------------------------------------
// k_setup: detect float dtype + mask format, canonicalize mask, count masked.
// ---------------------------------------------------------------------------
__global__ void k_setup(const void* gf, const void* mask_raw, int* mask_i,
                        int* flags, float* scal) {
  __shared__ int s_gt1, s_oth, s_cnt;
  int tid = threadIdx.x;
  if (tid == 0) { s_gt1 = 0; s_oth = 0; s_cnt = 0; }
  __syncthreads();
  const unsigned* mw = (const unsigned*)mask_raw;
  int gt1 = 0, oth = 0;
  for (int i = tid; i < 2048; i += 256) {
    unsigned w = mw[i];
    if (w > 1u) { gt1 = 1; if (w != 0x3F800000u) oth = 1; }
  }
  if (gt1) atomicOr(&s_gt1, 1);
  if (oth) atomicOr(&s_oth, 1);
  __syncthreads();
  int fmt = (!s_gt1) ? 0 : (!s_oth ? 1 : 2);  // 0=int32, 1=f32, 2=bytes
  int cnt = 0;
  for (int i = tid; i < Bn * P * NV; i += 256) {
    int m;
    if (fmt == 0)      m = ((const int*)mask_raw)[i] != 0;
    else if (fmt == 1) m = ((const float*)mask_raw)[i] != 0.0f;
    else               m = ((const unsigned char*)mask_raw)[i] != 0;
    mask_i[i] = m; cnt += m;
  }
  atomicAdd(&s_cnt, cnt);
  __syncthreads();
  if (tid == 0) {
    unsigned w = *(const unsigned*)gf;
    flags[0] = ((w & 0xFFFFu) == 0x3F80u) ? 1 : 0;
    flags[1] = s_cnt;
    scal[0] = 0.f;
  }
}

// ---------------------------------------------------------------------------
// k_prep: blocks 0..31 -> per-(b,v) stats; blocks 32.. -> gather biases,
// final-LN weights (fp32), b_proj (fp32), WpT (bf16 [t][d]), and ALL
// per-layer LN gamma/beta as fp32 (R10). lnAll: [l][phase][g:512|b:512].
// ---------------------------------------------------------------------------
__global__ void k_prep(const void* x, const void* bq, const void* bk,
                       const void* bv, const void* bo, const void* b1,
                       const void* b2, const void* gf, const void* bff,
                       const void* Wp, const void* bp, const void* g1,
                       const void* be1, const void* g2, const void* be2,
                       const int* flags, float* means, float* stdev,
                       float* biasf, float* lnw, unsigned short* WpT,
                       float* lnAll) {
  int bf = flags[0];
  int tid = threadIdx.x;
  if (blockIdx.x < 32) {
    int bv_ = blockIdx.x * 4 + (tid >> 6);
    int b = bv_ >> 5, v = bv_ & 31;
    int lane = tid & 63;
    float s = 0.f, s2 = 0.f;
    for (int t = lane; t < SEQ; t += 64) {
      float val = ldf(x, (size_t)b * SEQ * NV + (size_t)t * NV + v, bf);
      s += val; s2 += val * val;
    }
    for (int off = 32; off; off >>= 1) {
      s += __shfl_xor(s, off); s2 += __shfl_xor(s2, off);
    }
    if (lane == 0) {
      float m = s / (float)SEQ;
      means[bv_] = m;
      stdev[bv_] = sqrtf(s2 / (float)SEQ - m * m + 1e-5f);
    }
    return;
  }
  int i = (blockIdx.x - 32) * 256 + tid;
  if (i < 18432) {
    int l = i / 4608, r = i % 4608;
    if (r < 1536) {
      float v = (r < 512) ? ldf(bq, l * 512 + r, bf)
              : (r < 1024) ? ldf(bk, l * 512 + r - 512, bf)
                           : ldf(bv, l * 512 + r - 1024, bf);
      biasf[l * 1536 + r] = v;
    } else if (r < 2048) {
      biasf[6144 + l * 512 + (r - 1536)] = ldf(bo, l * 512 + r - 1536, bf);
    } else if (r < 4096) {
      biasf[8192 + l * 2048 + (r - 2048)] = ldf(b1, l * 2048 + r - 2048, bf);
    } else {
      biasf[16384 + l * 512 + (r - 4096)] = ldf(b2, l * 512 + r - 4096, bf);
    }
  } else if (i < 19456) {
    int j = i - 18432;
    lnw[j] = (j < 512) ? ldf(gf, j, bf) : ldf(bff, j - 512, bf);
  } else if (i < 19472) {
    lnw[1024 + (i - 19456)] = ldf(bp, i - 19456, bf);
  } else if (i < 27664) {
    int j = i - 19472; int t = j >> 9, d = j & 511;
    WpT[j] = f2b(ldf(Wp, d * 16 + t, bf));
  } else if (i < 35856) {
    int j = i - 27664;
    int l = j >> 11, r = j & 2047;
    int ph = r >> 10, c = r & 1023;
    const void* src = (c < 512) ? (ph ? g2 : g1) : (ph ? be2 : be1);
    lnAll[j] = ldf(src, l * 512 + (c & 511), bf);
  }
}

// ---------------------------------------------------------------------------
// k_transpose_all: all 6 weight transposes in one dispatch.
// dst[l][n][k] (bf16) = src[l][k][n]. 32x32 LDS tile per block.
// ---------------------------------------------------------------------------
__global__ void k_transpose_all(const void* Wq, const void* Wk, const void* Wv,
                                const void* Wo, const void* W1, const void* W2,
                                unsigned short* qkvT, unsigned short* WoT,
                                unsigned short* W1T, unsigned short* W2T,
                                const int* flags) {
  int bf = flags[0];
  int id = blockIdx.x;
  const void* src; unsigned short* dst;
  int Kd, Nd, l, n0, k0, dstOff = 0;
  size_t srcLS, dstLS;
  if (id < 4096) {
    int tensor = id >> 10, rem = id & 1023;
    l = rem >> 8; int t = rem & 255;
    n0 = (t & 15) * 32; k0 = (t >> 4) * 32;
    Kd = 512; Nd = 512; srcLS = 262144;
    if (tensor == 0)      { src = Wq; dst = qkvT; dstLS = 786432; dstOff = 0; }
    else if (tensor == 1) { src = Wk; dst = qkvT; dstLS = 786432; dstOff = 262144; }
    else if (tensor == 2) { src = Wv; dst = qkvT; dstLS = 786432; dstOff = 524288; }
    else                  { src = Wo; dst = WoT;  dstLS = 262144; }
  } else if (id < 8192) {
    int rem = id - 4096; l = rem >> 10; int t = rem & 1023;
    n0 = (t & 63) * 32; k0 = (t >> 6) * 32;
    Kd = 512; Nd = 2048; srcLS = 1048576; src = W1; dst = W1T; dstLS = 1048576;
  } else {
    int rem = id - 8192; l = rem >> 10; int t = rem & 1023;
    n0 = (t & 15) * 32; k0 = (t >> 4) * 32;
    Kd = 2048; Nd = 512; srcLS = 1048576; src = W2; dst = W2T; dstLS = 1048576;
  }
  int tx = threadIdx.x & 31, ty = threadIdx.x >> 5;
  __shared__ float tile[32][33];
  for (int rr = ty; rr < 32; rr += 8)
    tile[rr][tx] =
        ldf(src, (size_t)l * srcLS + (size_t)(k0 + rr) * Nd + n0 + tx, bf);
  __syncthreads();
  for (int rr = ty; rr < 32; rr += 8)
    dst[(size_t)l * dstLS + dstOff + (size_t)(n0 + rr) * Kd + k0 + tx] =
        f2b(tile[tx][rr]);
}

// ---------------------------------------------------------------------------
// k_embed (R11, kept): one block per (b,p) patch, 512 thr. We staged ONCE in
// LDS as float4 [t][d4] (32 KB). Thread (v = tid>>4, c = tid&15) computes
// token v, d4-set c+16k; ushort4 stores coalesce. Bit-identical math.
// ---------------------------------------------------------------------------
__global__ __launch_bounds__(512) void k_embed(
    const void* x, const void* We, const void* be, const int* flags,
    const int* mask_i, const float* means, const float* stdev,
    float* patches, unsigned short* tok) {
  int bp = blockIdx.x;              // Bn*P = 256 blocks
  int b = bp >> 6, p = bp & 63;
  int bf = flags[0];
  __shared__ float4v sWe[16 * 128];   // [t][d4], 32 KB
  __shared__ float4v sbe[128];
  __shared__ float spv[32][17];
  int tid = threadIdx.x;
  for (int i = tid; i < 2048; i += 512) {
    float4v w4;
    w4[0] = ldf(We, (size_t)i * 4 + 0, bf);
    w4[1] = ldf(We, (size_t)i * 4 + 1, bf);
    w4[2] = ldf(We, (size_t)i * 4 + 2, bf);
    w4[3] = ldf(We, (size_t)i * 4 + 3, bf);
    sWe[i] = w4;
  }
  if (tid < 128) {
    float4v b4;
    b4[0] = ldf(be, tid * 4 + 0, bf);
    b4[1] = ldf(be, tid * 4 + 1, bf);
    b4[2] = ldf(be, tid * 4 + 2, bf);
    b4[3] = ldf(be, tid * 4 + 3, bf);
    sbe[tid] = b4;
  }
  {
    int t = tid >> 5, v = tid & 31;
    float m = means[b * NV + v], sd = stdev[b * NV + v];
    float val =
        (ldf(x, (size_t)b * SEQ * NV + (size_t)(p * PL + t) * NV + v, bf) -
         m) / sd;
    spv[v][t] = val;
    patches[(size_t)((b << 11) + (p << 5) + v) * PL + t] = val;
  }
  __syncthreads();
  int v = tid >> 4, c = tid & 15;
  int idx = (b << 11) + (p << 5) + v;
  int masked = mask_i[idx];
  float pv[16];
#pragma unroll
  for (int t = 0; t < 16; t++) pv[t] = spv[v][t];
  unsigned short* orow = tok + (size_t)idx * D;
#pragma unroll
  for (int k = 0; k < 8; k++) {
    int d4 = c + (k << 4);
    float4v acc = sbe[d4];
#pragma unroll
    for (int t = 0; t < 16; t++) {
      float4v w4 = sWe[t * 128 + d4];
      acc[0] += pv[t] * w4[0];
      acc[1] += pv[t] * w4[1];
      acc[2] += pv[t] * w4[2];
      acc[3] += pv[t] * w4[3];
    }
    ushort4 ou;
    ou[0] = masked ? (unsigned short)0 : f2b(acc[0]);
    ou[1] = masked ? (unsigned short)0 : f2b(acc[1]);
    ou[2] = masked ? (unsigned short)0 : f2b(acc[2]);
    ou[3] = masked ? (unsigned short)0 : f2b(acc[3]);
    *(ushort4*)(orow + d4 * 4) = ou;
  }
}

// ---------------------------------------------------------------------------
// k_gemm<BM,BN,WN>: C = act(A @ W^T' + bias [+resid]) in bf16. BK=64.
// Linear grid, XCD-swizzled. Epilogue through LDS for coalesced ushort8 IO.
// R15: __launch_bounds__(256, 4). R11/R14 proved (256,3) nets -35 us vs
// plain: the clamped wide tile compiles to 56 arch + 64 acc = 120 unified
// VGPRs (slower inner loop but no scratch) and wins on residency. 120 fits
// the 128-reg budget of min-4-waves/SIMD, so (256,4) should reuse the same
// codegen with 4 blocks/CU instead of 3 -> more latency hiding. Fallback
// if WRITE_SIZE balloons (spill): revert to (256,3) exact R14.
// All constant-trip loops carry #pragma unroll (rule #20).
// ---------------------------------------------------------------------------
template <int BM, int BN, int WN>
__global__ __launch_bounds__(256, 4) void k_gemm(
    const unsigned short* __restrict__ A, const unsigned short* __restrict__ W,
    const float* __restrict__ bias, const unsigned short* __restrict__ resid,
    unsigned short* __restrict__ C, unsigned short* __restrict__ vTp, int cs,
    int Kk, int act, int nbn) {
  constexpr int FI = 4, FJ = WN / 16, NWN = BN / WN;
  __shared__ __align__(16) char sm[BM * 128 + BN * 128];
  char* As = sm;
  char* Bs = sm + BM * 128;
  unsigned short* Cl = (unsigned short*)sm;
  int tid = threadIdx.x, lane = tid & 63, w = tid >> 6;
  int lane15 = lane & 15, q = lane >> 4;
  int wm = w / NWN, wn = w % NWN;
  int id = blockIdx.x;
  int xcd = id & 7, loc = id >> 3;
  int bn = (loc % nbn) * BN;
  int bm = (xcd * ((int)(gridDim.x >> 3) / nbn) + loc / nbn) * BM;
  int lrow = lane >> 3, lc = lane & 7;
  float4v acc[FI][FJ];
#pragma unroll
  for (int i = 0; i < FI; i++)
#pragma unroll
    for (int j = 0; j < FJ; j++) acc[i][j] = 0;
  for (int k0 = 0; k0 < Kk; k0 += 64) {
    if (k0) __syncthreads();
    for (int i = w; i < BM / 8; i += 4) {
      int row = i * 8 + lrow;
      gll16(A + (size_t)(bm + row) * Kk + k0 + ((lc ^ (row & 7)) << 3),
            As + i * 1024);
    }
    for (int i = w; i < BN / 8; i += 4) {
      int row = i * 8 + lrow;
      gll16(W + (size_t)(bn + row) * Kk + k0 + ((lc ^ (row & 7)) << 3),
            Bs + i * 1024);
    }
    __syncthreads();
    short8 a[2][FI], b[2][FJ];
#pragma unroll
    for (int h = 0; h < 2; h++) {
#pragma unroll
      for (int i = 0; i < FI; i++) {
        int rr = wm * 64 + i * 16 + lane15;
        a[h][i] =
            *(const short8*)(As + rr * 128 + (((h * 4 + q) ^ (rr & 7)) << 4));
      }
#pragma unroll
      for (int j = 0; j < FJ; j++) {
        int rr = wn * WN + j * 16 + lane15;
        b[h][j] =
            *(const short8*)(Bs + rr * 128 + (((h * 4 + q) ^ (rr & 7)) << 4));
      }
    }
#pragma unroll
    for (int h = 0; h < 2; h++)
#pragma unroll
      for (int i = 0; i < FI; i++)
#pragma unroll
        for (int j = 0; j < FJ; j++)
          acc[i][j] = __builtin_amdgcn_mfma_f32_16x16x32_bf16(
              a[h][i], b[h][j], acc[i][j], 0, 0, 0);
  }
  // ---- epilogue through LDS ----
  int vmode = (vTp != nullptr) && (bn >= 1024);
  float oscale = (vTp != nullptr && bn < 512) ? 0.125f : 1.0f;  // q pre-scale
  __syncthreads();  // all MFMAs done reading As/Bs
#pragma unroll
  for (int i = 0; i < FI; i++) {
#pragma unroll
    for (int j = 0; j < FJ; j++) {
      int col = wn * WN + j * 16 + lane15;        // tile-local col
      float bv = bias[bn + col];
#pragma unroll
      for (int r = 0; r < 4; r++) {
        int row = wm * 64 + i * 16 + q * 4 + r;   // tile-local row
        float cv = (acc[i][j][r] + bv) * oscale;
        if (act) {  // fast GELU: x * sigmoid(1.5958x + 0.07135x^3)
          float t = cv * (1.5957692f + 0.0713548f * cv * cv);
          cv = cv / (1.f + __expf(-t));
        }
        if (!vmode)
          Cl[row * BN + (((col >> 3) ^ (row & 7)) << 3) + (col & 7)] = f2bt(cv);
        else
          Cl[col * BM + (((row >> 3) ^ (col & 7)) << 3) + (row & 7)] = f2bt(cv);
      }
    }
  }
  __syncthreads();
  if (!vmode) {
    constexpr int TOT = BM * BN / 8;
    for (int e = tid; e < TOT; e += 256) {
      int rr = e / (BN / 8), c8 = e % (BN / 8);
      ushort8 u = *(const ushort8*)(Cl + rr * BN + ((c8 ^ (rr & 7)) << 3));
      size_t off = (size_t)(bm + rr) * cs + bn + c8 * 8;
      if (resid) {
        ushort8 rv = *(const ushort8*)(resid + off);
#pragma unroll
        for (int t = 0; t < 8; t++) u[t] = f2bt(b2f(u[t]) + b2f(rv[t]));
      }
      *(ushort8*)(C + off) = u;
    }
  } else {
    constexpr int TOT = BM * BN / 8;
    for (int e = tid; e < TOT; e += 256) {
      int cc = e / (BM / 8), t8 = e % (BM / 8);
      ushort8 u = *(const ushort8*)(Cl + cc * BM + ((t8 ^ (cc & 7)) << 3));
      int hd = bn - 1024 + cc;
      int rowg = bm + t8 * 8;
      int bb = rowg >> 11, tokin = rowg & 2047;
      *(ushort8*)(vTp + ((size_t)(bb * 512 + hd)) * 2048 + tokin) = u;
    }
  }
}

// ---------------------------------------------------------------------------
// k_attn: banded MFMA attention, fragment-direct global loads. 19.5 KB LDS,
// VGPR <64 -> 8 blocks/CU. q pre-scaled by 0.125 in QKV GEMM; softmax skips
// max-sub (|s| <~ 5). T5 s_setprio(1) around MFMA clusters (R10 win).
// ---------------------------------------------------------------------------
__global__ __launch_bounds__(256) void k_attn(
    const unsigned short* __restrict__ qk,
    const unsigned short* __restrict__ vT, unsigned short* __restrict__ o) {
  constexpr int SSTR = 304;
  __shared__ __align__(16) unsigned short S[32 * SSTR];
  int id = blockIdx.x;
  int xcd = id & 7, rr_ = id >> 3;
  int p = xcd * 8 + (rr_ & 7);
  int h = (rr_ >> 3) & 7;
  int b = rr_ >> 6;
  int tid = threadIdx.x, lane = tid & 63, w = tid >> 6;
  int lane15 = lane & 15, q = lane >> 4;
  int p0 = max(0, p - WIN), p1 = min(P - 1, p + WIN);
  int nk = (p1 - p0 + 1) * 32;     // multiple of 32, in [160,288]
  int ntiles = nk >> 4;
  size_t base = (size_t)b * L;
  // Q fragments for BOTH m-tiles (A-operand), direct global
  short8 aq[2][2];
  for (int m = 0; m < 2; m++) {
    const unsigned short* qrow =
        qk + (base + p * 32 + m * 16 + lane15) * 1024 + h * 64 + q * 8;
    aq[m][0] = *(const short8*)(qrow);
    aq[m][1] = *(const short8*)(qrow + 32);
  }
  const unsigned short* kbase =
      qk + (base + p0 * 32) * 1024 + 512 + h * 64 + q * 8;
  // phase A: wave w handles nt = w, w+4, ... (no duplicate K loads)
  {
    int nt = w;
    const unsigned short* kr = kbase + (size_t)(nt * 16 + lane15) * 1024;
    short8 c0, c1, n0, n1;
    if (nt < ntiles) {
      c0 = *(const short8*)(kr);
      c1 = *(const short8*)(kr + 32);
    }
    if (nt + 4 < ntiles) {
      kr = kbase + (size_t)((nt + 4) * 16 + lane15) * 1024;
      n0 = *(const short8*)(kr);
      n1 = *(const short8*)(kr + 32);
    }
    for (; nt < ntiles; nt += 4) {
      short8 m0, m1;
      if (nt + 8 < ntiles) {
        kr = kbase + (size_t)((nt + 8) * 16 + lane15) * 1024;
        m0 = *(const short8*)(kr);
        m1 = *(const short8*)(kr + 32);
      }
      __builtin_amdgcn_s_setprio(1);
      for (int m = 0; m < 2; m++) {
        float4v s4 = 0;
        s4 = __builtin_amdgcn_mfma_f32_16x16x32_bf16(aq[m][0], c0, s4, 0, 0, 0);
        s4 = __builtin_amdgcn_mfma_f32_16x16x32_bf16(aq[m][1], c1, s4, 0, 0, 0);
        for (int r = 0; r < 4; r++)
          S[(m * 16 + q * 4 + r) * SSTR + nt * 16 + lane15] = f2b(s4[r]);
      }
      __builtin_amdgcn_s_setprio(0);
      c0 = n0; c1 = n1; n0 = m0; n1 = m1;
    }
  }
  __syncthreads();
  // phase B: softmax without max-sub, b128 LDS IO, trunc P pack
  {
    int row = tid >> 3, c = tid & 7;
    ushort8 eb[5];
    float sum = 0.f;
    for (int k = 0; k < 5; k++) {
      int j0 = c * 8 + k * 64;
      if (j0 < nk) {
        ushort8 u = *(const ushort8*)(S + row * SSTR + j0);
        ushort8 e8;
        for (int t = 0; t < 8; t++) {
          float e = __expf(b2f(u[t]));
          sum += e;
          e8[t] = f2bt(e);
        }
        eb[k] = e8;
      }
    }
    for (int off = 1; off < 8; off <<= 1) sum += __shfl_xor(sum, off);
    float inv = 1.f / sum;
    for (int k = 0; k < 5; k++) {
      int j0 = c * 8 + k * 64;
      if (j0 < nk) {
        ushort8 e8 = eb[k], u;
        for (int t = 0; t < 8; t++) u[t] = f2bt(b2f(e8[t]) * inv);
        *(ushort8*)(S + row * SSTR + j0) = u;
      }
    }
  }
  __syncthreads();
  // phase C: O = P V. Wave w owns column tile w (16 cols), both m-tiles --
  // one V load per kt feeds 2 MFMAs (no duplicate V loads across waves).
  int nkt = nk >> 5;
  const unsigned short* vb =
      vT + (size_t)(b * 512 + h * 64 + w * 16 + lane15) * 2048 + p0 * 32 +
      q * 8;
  const unsigned short* pr0 = S + lane15 * SSTR + q * 8;
  const unsigned short* pr1 = S + (16 + lane15) * SSTR + q * 8;
  float4v oa0 = 0, oa1 = 0;
  short8 ap0 = *(const short8*)(pr0);
  short8 ap1 = *(const short8*)(pr1);
  short8 v0 = *(const short8*)(vb);
  for (int kt = 0; kt < nkt; kt++) {
    short8 a0N, a1N, v0N;
    if (kt + 1 < nkt) {
      a0N = *(const short8*)(pr0 + (kt + 1) * 32);
      a1N = *(const short8*)(pr1 + (kt + 1) * 32);
      v0N = *(const short8*)(vb + (kt + 1) * 32);
    }
    __builtin_amdgcn_s_setprio(1);
    oa0 = __builtin_amdgcn_mfma_f32_16x16x32_bf16(ap0, v0, oa0, 0, 0, 0);
    oa1 = __builtin_amdgcn_mfma_f32_16x16x32_bf16(ap1, v0, oa1, 0, 0, 0);
    __builtin_amdgcn_s_setprio(0);
    ap0 = a0N; ap1 = a1N; v0 = v0N;
  }
  // stage O in LDS (reuse S), then store full 128B lines cooperatively
  __syncthreads();
  for (int r = 0; r < 4; r++) {
    S[(q * 4 + r) * 72 + w * 16 + lane15] = f2bt(oa0[r]);
    S[(16 + q * 4 + r) * 72 + w * 16 + lane15] = f2bt(oa1[r]);
  }
  __syncthreads();
  {
    int row = tid >> 3, c8 = tid & 7;
    ushort8 val = *(const ushort8*)(S + row * 72 + c8 * 8);
    *(ushort8*)(o + (base + p * 32 + row) * 512 + h * 64 + c8 * 8) = val;
  }
}

// ---------------------------------------------------------------------------
// k_ln: layernorm over D=512 per token, bf16 in/out. 4 rows per block.
// gamma/beta pre-converted to fp32 (lnAll) -> float4 loads (R10).
// ---------------------------------------------------------------------------
__global__ void k_ln(const unsigned short* __restrict__ x,
                     const float* __restrict__ gb,
                     unsigned short* __restrict__ out) {
  int row = blockIdx.x * 4 + (threadIdx.x >> 6);
  int lane = threadIdx.x & 63;
  ushort8 u = *(const ushort8*)(x + (size_t)row * D + lane * 8);
  float v[8]; float s = 0.f, s2 = 0.f;
#pragma unroll
  for (int t = 0; t < 8; t++) {
    v[t] = b2f(u[t]); s += v[t]; s2 += v[t] * v[t];
  }
  for (int off = 32; off; off >>= 1) {
    s += __shfl_xor(s, off); s2 += __shfl_xor(s2, off);
  }
  float m = s / (float)D;
  float inv = rsqrtf(s2 / (float)D - m * m + 1e-5f);
  float4v g0 = *(const float4v*)(gb + lane * 8);
  float4v g1v = *(const float4v*)(gb + lane * 8 + 4);
  float4v b0 = *(const float4v*)(gb + 512 + lane * 8);
  float4v b1v = *(const float4v*)(gb + 512 + lane * 8 + 4);
  float g[8] = {g0[0], g0[1], g0[2], g0[3], g1v[0], g1v[1], g1v[2], g1v[3]};
  float bb[8] = {b0[0], b0[1], b0[2], b0[3], b1v[0], b1v[1], b1v[2], b1v[3]};
  ushort8 ou;
#pragma unroll
  for (int t = 0; t < 8; t++) {
    ou[t] = f2b((v[t] - m) * inv * g[t] + bb[t]);
  }
  *(ushort8*)(out + (size_t)row * D + lane * 8) = ou;
}

// ---------------------------------------------------------------------------
// k_lnloss: fused final LN + recon head (MFMA) + masked MSE.
// ---------------------------------------------------------------------------
__global__ __launch_bounds__(128) void k_lnloss(
    const unsigned short* __restrict__ tok, const float* __restrict__ lnw,
    const unsigned short* __restrict__ WpT, const float* __restrict__ patches,
    const float* __restrict__ stdev, const int* __restrict__ mask_i,
    float* scal) {
  constexpr int RS = 520;  // padded LDS row stride (elements)
  __shared__ __align__(16) unsigned short As[32 * RS];
  __shared__ __align__(16) unsigned short Bs[16 * RS];
  int bpI = blockIdx.x; int b = bpI >> 6, p = bpI & 63;
  int tid = threadIdx.x;
  int row = tid >> 2, cg = tid & 3;   // 4 threads per token row
  size_t tokbase = (size_t)(b * L + p * 32);
  float s = 0.f, s2 = 0.f;
  for (int i = 0; i < 16; i++) {
    int c = cg + i * 4;
    ushort8 u = *(const ushort8*)(tok + (tokbase + row) * D + c * 8);
    for (int t = 0; t < 8; t++) { float v = b2f(u[t]); s += v; s2 += v * v; }
  }
  s += __shfl_xor(s, 1); s += __shfl_xor(s, 2);
  s2 += __shfl_xor(s2, 1); s2 += __shfl_xor(s2, 2);
  float m = s / (float)D;
  float inv = rsqrtf(s2 / (float)D - m * m + 1e-5f);
  for (int i = 0; i < 16; i++) {
    int c = cg + i * 4;
    ushort8 u = *(const ushort8*)(tok + (tokbase + row) * D + c * 8);
    ushort8 o;
    for (int t = 0; t < 8; t++) {
      int col = c * 8 + t;
      o[t] = f2b((b2f(u[t]) - m) * inv * lnw[col] + lnw[512 + col]);
    }
    *(ushort8*)(As + row * RS + c * 8) = o;
  }
  for (int e = tid; e < 16 * 64; e += 128) {
    int r = e >> 6, c = e & 63;
    *(ushort8*)(Bs + r * RS + c * 8) = *(const ushort8*)(WpT + r * 512 + c * 8);
  }
  __syncthreads();
  int w = tid >> 6, lane = tid & 63, lane15 = lane & 15, q = lane >> 4;
  float4v acc = 0;
  for (int kt = 0; kt < 16; kt++) {
    short8 a = *(const short8*)(As + (w * 16 + lane15) * RS + kt * 32 + q * 8);
    short8 bfr = *(const short8*)(Bs + lane15 * RS + kt * 32 + q * 8);
    acc = __builtin_amdgcn_mfma_f32_16x16x32_bf16(a, bfr, acc, 0, 0, 0);
  }
  float local = 0.f;
  int t = lane15;
  for (int r = 0; r < 4; r++) {
    int v = w * 16 + q * 4 + r;
    int tokidx = b * 2048 + p * 32 + v;
    if (mask_i[tokidx]) {
      float recon = acc[r] + lnw[1024 + t];
      float diff = recon - patches[(size_t)tokidx * 16 + t];
      float sc = stdev[b * 32 + v];
      local += sc * sc * diff * diff;
    }
  }
  for (int off = 32; off; off >>= 1) local += __shfl_xor(local, off);
  if (lane == 0) atomicAdd(&scal[0], local);
}

__global__ void k_final(const float* scal, const int* flags, unsigned* out) {
  float denom = (float)flags[1] * (float)PL;
  if (denom == 0.f) denom = 1.f;
  float loss = scal[0] / denom;
  unsigned fb = __float_as_uint(loss);
  unsigned u = (fb + 0x7FFFu + ((fb >> 16) & 1u)) >> 16;
  out[0] = (u << 16) | u;
}

}  // namespace

extern "C" void kernel_launch(void* const* d_in, const int* in_sizes, int n_in,
                              void* d_out, int out_size, void* d_ws,
                              size_t ws_size, hipStream_t stream) {
  const void* x_enc = d_in[0];
  const void* maskp = d_in[1];
  const void* We = d_in[2];  const void* be_ = d_in[3];
  const void* Wq = d_in[4];  const void* bq = d_in[5];
  const void* Wk = d_in[6];  const void* bk = d_in[7];
  const void* Wv = d_in[8];  const void* bv = d_in[9];
  const void* Wo = d_in[10]; const void* bo_ = d_in[11];
  const void* W1 = d_in[12]; const void* b1 = d_in[13];
  const void* W2 = d_in[14]; const void* b2 = d_in[15];
  const void* g1 = d_in[16]; const void* be1 = d_in[17];
  const void* g2 = d_in[18]; const void* be2 = d_in[19];
  const void* gf = d_in[20]; const void* bff = d_in[21];
  const void* Wp = d_in[22]; const void* bp = d_in[23];

  constexpr size_t MB = 1u << 20;
  char* w = (char*)d_ws;
  int*   mask_i  = (int*)w;                        // 32 KB
  int*   flags   = (int*)(w + 32768);
  float* scal    = (float*)(w + 32896);
  float* means   = (float*)(w + 33024);
  float* stdev   = (float*)(w + 33600);
  float* biasf   = (float*)(w + 36864);            // 73728 B -> ends 110592
  float* lnw     = (float*)(w + 114688);           // 4160 B
  float* patches = (float*)(w + 131072);           // 512 KB -> ends 655360
  unsigned short* WpT = (unsigned short*)(w + 655360);    // 16 KB -> 671744
  float* lnAllF  = (float*)(w + 688128);           // 32 KB -> ends 720896
  unsigned short* qkvT = (unsigned short*)(w + 1 * MB);   // 6 MB
  unsigned short* WoT  = (unsigned short*)(w + 7 * MB);   // 2 MB
  unsigned short* W1T  = (unsigned short*)(w + 9 * MB);   // 8 MB
  unsigned short* W2T  = (unsigned short*)(w + 17 * MB);  // 8 MB
  unsigned short* tok  = (unsigned short*)(w + 25 * MB);  // 8 MB
  unsigned short* tmp  = (unsigned short*)(w + 33 * MB);  // 8 MB
  unsigned short* ob   = (unsigned short*)(w + 41 * MB);  // 8 MB
  unsigned short* qk   = (unsigned short*)(w + 49 * MB);  // 16 MB -> ends 65
  unsigned short* vTb  = (unsigned short*)(w + 73 * MB);  // 8 MB -> ends 81
  unsigned short* hidden = ob;   // 32 MB alias over ob+qk (dead by FFN1)

  k_setup<<<1, 256, 0, stream>>>(gf, maskp, mask_i, flags, scal);
  k_prep<<<173, 256, 0, stream>>>(x_enc, bq, bk, bv, bo_, b1, b2, gf, bff, Wp,
                                  bp, g1, be1, g2, be2, flags, means, stdev,
                                  biasf, lnw, WpT, lnAllF);
  k_transpose_all<<<12288, 256, 0, stream>>>(Wq, Wk, Wv, Wo, W1, W2, qkvT, WoT,
                                             W1T, W2T, flags);
  k_embed<<<Bn * P, 512, 0, stream>>>(x_enc, We, be_, flags, mask_i, means,
                                      stdev, patches, tok);
  for (int l = 0; l < 4; l++) {
    // QKV: M=8192, N=1536, K=512 -> <128,128,64>, grid 768
    k_gemm<128, 128, 64><<<768, 256, 0, stream>>>(
        tok, qkvT + (size_t)l * 786432, biasf + l * 1536, nullptr, qk, vTb,
        1024, 512, 0, 12);
    k_attn<<<2048, 256, 0, stream>>>(qk, vTb, ob);
    // Wo: N=512, K=512 -> skinny <64,64,16> @1024 blocks
    k_gemm<64, 64, 16><<<1024, 256, 0, stream>>>(
        ob, WoT + (size_t)l * 262144, biasf + 6144 + l * 512, tok, tmp,
        nullptr, 512, 512, 0, 8);
    k_ln<<<M / 4, 256, 0, stream>>>(tmp, lnAllF + (size_t)(l * 2) * 1024, tok);
    // FFN1: M=8192, N=2048, K=512 -> <128,128,64>, grid 1024
    k_gemm<128, 128, 64><<<1024, 256, 0, stream>>>(
        tok, W1T + (size_t)l * 1048576, biasf + 8192 + l * 2048, nullptr,
        hidden, nullptr, 2048, 512, 1, 16);
    // FFN2: N=512, K=2048 -> skinny <64,64,16> @1024
    k_gemm<64, 64, 16><<<1024, 256, 0, stream>>>(
        hidden, W2T + (size_t)l * 1048576, biasf + 16384 + l * 512, tok, tmp,
        nullptr, 512, 2048, 0, 8);
    k_ln<<<M / 4, 256, 0, stream>>>(tmp, lnAllF + (size_t)(l * 2 + 1) * 1024,
                                    tok);
  }
  k_lnloss<<<Bn * P, 128, 0, stream>>>(tok, lnw, WpT, patches, stdev, mask_i,
                                       scal);
  k_final<<<1, 1, 0, stream>>>(scal, flags, (unsigned*)d_out);
}